// Round 7
// baseline (719.772 us; speedup 1.0000x reference)
//
#include <hip/hip_runtime.h>
#include <hip/hip_bf16.h>
#include <math.h>

#define TSEQ 2048
#define HEADS 16
#define HSZ 64
#define CDIM 1024
#define MROWS 4096   // B*T
#define CHUNK 64
#define NCHUNK (TSEQ/CHUNK)   // 32
#define NBH 32                // B*HEADS
#define LSTR 68               // LDS row stride (shorts) for 64-wide bf16 mats

typedef short bf16x8 __attribute__((ext_vector_type(8)));
typedef short bf16x4 __attribute__((ext_vector_type(4)));
typedef float f32x4 __attribute__((ext_vector_type(4)));

__device__ __forceinline__ float sigf(float x) { return 1.0f / (1.0f + expf(-x)); }

__device__ __forceinline__ short to_bf16(float f) {
    __hip_bfloat16 h = __float2bfloat16(f);
    return *reinterpret_cast<short*>(&h);
}
__device__ __forceinline__ float bf2f(short s) {
    unsigned int u = ((unsigned int)(unsigned short)s) << 16;
    return __uint_as_float(u);
}

// ---------------------------------------------------------------------------
// Weight transpose + f32->bf16 convert:  W [K,N] f32  ->  Wt [N,K] bf16
// ---------------------------------------------------------------------------
__global__ __launch_bounds__(256)
void transpose_cvt(const float* __restrict__ W, short* __restrict__ Wt,
                   const int K, const int N)
{
    __shared__ float t[32][33];
    const int k0 = blockIdx.y * 32, n0 = blockIdx.x * 32;
    const int lx = threadIdx.x & 31, ly = threadIdx.x >> 5;   // ly 0..7
#pragma unroll
    for (int i = 0; i < 4; ++i)
        t[ly + i*8][lx] = W[(size_t)(k0 + ly + i*8)*N + n0 + lx];
    __syncthreads();
#pragma unroll
    for (int i = 0; i < 4; ++i)
        Wt[(size_t)(n0 + ly + i*8)*K + k0 + lx] = to_bf16(t[lx][ly + i*8]);
}

// ---------------------------------------------------------------------------
// bf16 MFMA GEMM:  C[M,N] = act( A'[M,K] @ Bt[N,K]^T )   (round-4, verified)
// ---------------------------------------------------------------------------
template<int BN, int ACT, bool MIX, bool OBF16>
__global__ __launch_bounds__(256)
void gemm_mfma(const void* __restrict__ Aptr, const short* __restrict__ Bt,
               void* __restrict__ Cptr, const int M, const int N, const int K,
               const float* __restrict__ mixv)
{
    constexpr int BM = 128, BK = 32;
    constexpr int ASTR = BK + 8;
    constexpr int NWC = (BN >= 128) ? 2 : 1;
    constexpr int NWR = 4 / NWC;
    constexpr int WM = BM / NWR;
    constexpr int WN = BN / NWC;
    constexpr int AM = WM / 16;
    constexpr int AN = WN / 16;

    __shared__ short As[BM * ASTR];
    __shared__ short Bs[BN * ASTR];

    const int tid  = threadIdx.x;
    const int bm   = blockIdx.y * BM;
    const int bn   = blockIdx.x * BN;
    const int wid  = tid >> 6;
    const int lane = tid & 63;
    const int wr   = wid / NWC;
    const int wc   = wid % NWC;
    const int lrow = lane & 15;
    const int koff = (lane >> 4) * 8;

    f32x4 acc[AM][AN];
#pragma unroll
    for (int m = 0; m < AM; ++m)
#pragma unroll
        for (int n = 0; n < AN; ++n)
            acc[m][n] = (f32x4){0.f, 0.f, 0.f, 0.f};

    for (int k0 = 0; k0 < K; k0 += BK) {
        __syncthreads();
        if (MIX) {
            const float* A = (const float*)Aptr;
#pragma unroll
            for (int p = 0; p < (BM*BK)/(256*4); ++p) {
                const int flat = p*1024 + tid*4;
                const int row = flat >> 5;
                const int kc  = flat & 31;
                const int m   = bm + row;
                const float* xp = A + (size_t)m*K + k0 + kc;
                float4 xv = *(const float4*)xp;
                float4 xs = make_float4(0.f, 0.f, 0.f, 0.f);
                if ((m & (TSEQ-1)) != 0) xs = *(const float4*)(xp - K);
                const float4 mv = *(const float4*)(mixv + k0 + kc);
                xv.x += (xs.x - xv.x) * mv.x;
                xv.y += (xs.y - xv.y) * mv.y;
                xv.z += (xs.z - xv.z) * mv.z;
                xv.w += (xs.w - xv.w) * mv.w;
                bf16x4 o;
                o[0] = to_bf16(xv.x); o[1] = to_bf16(xv.y);
                o[2] = to_bf16(xv.z); o[3] = to_bf16(xv.w);
                *(bf16x4*)&As[row*ASTR + kc] = o;
            }
        } else {
            const short* A = (const short*)Aptr;
#pragma unroll
            for (int p = 0; p < (BM*BK)/(256*8); ++p) {
                const int c = p*256 + tid;
                const int row = c >> 2;
                const int kc  = (c & 3) * 8;
                *(bf16x8*)&As[row*ASTR + kc] =
                    *(const bf16x8*)(A + (size_t)(bm+row)*K + k0 + kc);
            }
        }
        {
            constexpr int CHUNKS = (BN*BK)/8;
#pragma unroll
            for (int p = 0; p < (CHUNKS + 255)/256; ++p) {
                const int c = p*256 + tid;
                if ((CHUNKS & 255) == 0 || c < CHUNKS) {
                    const int col = c >> 2;
                    const int kc  = (c & 3) * 8;
                    *(bf16x8*)&Bs[col*ASTR + kc] =
                        *(const bf16x8*)(Bt + (size_t)(bn+col)*K + k0 + kc);
                }
            }
        }
        __syncthreads();

        bf16x8 af[AM], bfv[AN];
#pragma unroll
        for (int m = 0; m < AM; ++m)
            af[m] = *(const bf16x8*)&As[(wr*WM + m*16 + lrow)*ASTR + koff];
#pragma unroll
        for (int n = 0; n < AN; ++n)
            bfv[n] = *(const bf16x8*)&Bs[(wc*WN + n*16 + lrow)*ASTR + koff];
#pragma unroll
        for (int m = 0; m < AM; ++m)
#pragma unroll
            for (int n = 0; n < AN; ++n)
                acc[m][n] = __builtin_amdgcn_mfma_f32_16x16x32_bf16(
                    af[m], bfv[n], acc[m][n], 0, 0, 0);
    }

    const int r0 = (lane >> 4) * 4;
#pragma unroll
    for (int m = 0; m < AM; ++m) {
#pragma unroll
        for (int n = 0; n < AN; ++n) {
#pragma unroll
            for (int j = 0; j < 4; ++j) {
                const int row = bm + wr*WM + m*16 + r0 + j;
                const int col = bn + wc*WN + n*16 + lrow;
                float vv = acc[m][n][j];
                if (ACT == 1) vv = tanhf(vv);
                else if (ACT == 2) vv = sigf(vv);
                if (OBF16) ((short*)Cptr)[(size_t)row*N + col] = to_bf16(vv);
                else       ((float*)Cptr)[(size_t)row*N + col] = vv;
            }
        }
    }
}

// ---------------------------------------------------------------------------
// Per-row post-processing (round-6, verified)
// ---------------------------------------------------------------------------
__global__ __launch_bounds__(256)
void post_kernel(const float* __restrict__ tw, const float* __restrict__ vv,
                 const float* __restrict__ aa,
                 const float* __restrict__ w0, const float* __restrict__ v0p,
                 const float* __restrict__ a0p,
                 const float* __restrict__ k_k, const float* __restrict__ k_a,
                 const float* __restrict__ vfirst,
                 float* __restrict__ kio, float* __restrict__ vio,
                 float* __restrict__ dout, float* __restrict__ kkout,
                 float* __restrict__ bout)
{
    const int m  = blockIdx.x;
    const int c4 = threadIdx.x;
    const size_t o4 = (size_t)m*256 + c4;
    const int cc = c4*4;

    const float4 twv = ((const float4*)tw)[o4];
    const float4 vvv = ((const float4*)vv)[o4];
    const float4 aav = ((const float4*)aa)[o4];
    const float4 kv  = ((const float4*)kio)[o4];
    const float4 vv0 = ((const float4*)vio)[o4];
    const float4 vfv = ((const float4*)vfirst)[o4];
    const float4 w0v = *(const float4*)(w0 + cc);
    const float4 v0v = *(const float4*)(v0p + cc);
    const float4 a0v = *(const float4*)(a0p + cc);
    const float4 kkc = *(const float4*)(k_k + cc);
    const float4 kac = *(const float4*)(k_a + cc);

    float dec[4], vnew[4], av[4], kkr[4], knew[4];
    const float tws[4] = {twv.x, twv.y, twv.z, twv.w};
    const float vvs[4] = {vvv.x, vvv.y, vvv.z, vvv.w};
    const float aas[4] = {aav.x, aav.y, aav.z, aav.w};
    const float ks[4]  = {kv.x, kv.y, kv.z, kv.w};
    const float vs[4]  = {vv0.x, vv0.y, vv0.z, vv0.w};
    const float vfs[4] = {vfv.x, vfv.y, vfv.z, vfv.w};
    const float w0s[4] = {w0v.x, w0v.y, w0v.z, w0v.w};
    const float v0s[4] = {v0v.x, v0v.y, v0v.z, v0v.w};
    const float a0s[4] = {a0v.x, a0v.y, a0v.z, a0v.w};
    const float kks[4] = {kkc.x, kkc.y, kkc.z, kkc.w};
    const float kas[4] = {kac.x, kac.y, kac.z, kac.w};

    float ss = 0.f;
#pragma unroll
    for (int i = 0; i < 4; ++i) {
        dec[i]  = expf(-0.6065306597126334f * sigf(w0s[i] + tws[i]));
        const float sv = sigf(v0s[i] + vvs[i]);
        vnew[i] = vs[i] + (vfs[i] - vs[i]) * sv;
        av[i]   = sigf(a0s[i] + aas[i]);
        kkr[i]  = ks[i] * kks[i];
        knew[i] = ks[i] * (1.f + (av[i] - 1.f) * kas[i]);
        ss = fmaf(kkr[i], kkr[i], ss);
    }
#pragma unroll
    for (int mask = 1; mask < 16; mask <<= 1) ss += __shfl_xor(ss, mask);
    const float inv = fmaxf(rsqrtf(ss + 1e-12f), 1e-12f);

    float4 decv, vnv, knv, kkv4, bv4;
    decv.x = dec[0]; decv.y = dec[1]; decv.z = dec[2]; decv.w = dec[3];
    vnv.x = vnew[0]; vnv.y = vnew[1]; vnv.z = vnew[2]; vnv.w = vnew[3];
    knv.x = knew[0]; knv.y = knew[1]; knv.z = knew[2]; knv.w = knew[3];
    kkv4.x = kkr[0]*inv; kkv4.y = kkr[1]*inv; kkv4.z = kkr[2]*inv; kkv4.w = kkr[3]*inv;
    bv4.x = kkv4.x*av[0]; bv4.y = kkv4.y*av[1]; bv4.z = kkv4.z*av[2]; bv4.w = kkv4.w*av[3];

    ((float4*)dout)[o4]  = decv;
    ((float4*)vio)[o4]   = vnv;
    ((float4*)kio)[o4]   = knv;
    ((float4*)kkout)[o4] = kkv4;
    ((float4*)bout)[o4]  = bv4;
}

// ---------------------------------------------------------------------------
// MFMA helpers (round-5, verified): 64x64x64 GEMM by ONE wave,
// result[m][n] = sum_k A[m][k] * B[n][k]  (both row-major, stride LSTR)
// ---------------------------------------------------------------------------
__device__ __forceinline__ void zero44(f32x4 a[4][4]) {
#pragma unroll
    for (int m = 0; m < 4; ++m)
#pragma unroll
        for (int n = 0; n < 4; ++n) a[m][n] = (f32x4){0.f, 0.f, 0.f, 0.f};
}

__device__ __forceinline__ void mm_nt_lds(const short* __restrict__ Ab,
                                          const short* __restrict__ Bb,
                                          f32x4 acc[4][4], const int lane)
{
    const int lrow = lane & 15;
    const int ko   = (lane >> 4) * 8;
#pragma unroll
    for (int kh = 0; kh < 2; ++kh) {
        bf16x8 af[4], bfv[4];
#pragma unroll
        for (int m = 0; m < 4; ++m)
            af[m] = *(const bf16x8*)&Ab[(m*16 + lrow)*LSTR + kh*32 + ko];
#pragma unroll
        for (int n = 0; n < 4; ++n)
            bfv[n] = *(const bf16x8*)&Bb[(n*16 + lrow)*LSTR + kh*32 + ko];
#pragma unroll
        for (int m = 0; m < 4; ++m)
#pragma unroll
            for (int n = 0; n < 4; ++n)
                acc[m][n] = __builtin_amdgcn_mfma_f32_16x16x32_bf16(
                    af[m], bfv[n], acc[m][n], 0, 0, 0);
    }
}

// B operand from GLOBAL f32 [64][64] row-major, converted on the fly
__device__ __forceinline__ void mm_nt_gf32(const short* __restrict__ Ab,
                                           const float* __restrict__ Bg,
                                           f32x4 acc[4][4], const int lane)
{
    const int lrow = lane & 15;
    const int ko   = (lane >> 4) * 8;
#pragma unroll
    for (int kh = 0; kh < 2; ++kh) {
        bf16x8 af[4], bfv[4];
#pragma unroll
        for (int m = 0; m < 4; ++m)
            af[m] = *(const bf16x8*)&Ab[(m*16 + lrow)*LSTR + kh*32 + ko];
#pragma unroll
        for (int n = 0; n < 4; ++n) {
            const float* p = Bg + (size_t)(n*16 + lrow)*64 + kh*32 + ko;
            const float4 u0 = *(const float4*)p;
            const float4 u1 = *(const float4*)(p + 4);
            bf16x8 bv;
            bv[0] = to_bf16(u0.x); bv[1] = to_bf16(u0.y);
            bv[2] = to_bf16(u0.z); bv[3] = to_bf16(u0.w);
            bv[4] = to_bf16(u1.x); bv[5] = to_bf16(u1.y);
            bv[6] = to_bf16(u1.z); bv[7] = to_bf16(u1.w);
            bfv[n] = bv;
        }
#pragma unroll
        for (int m = 0; m < 4; ++m)
#pragma unroll
            for (int n = 0; n < 4; ++n)
                acc[m][n] = __builtin_amdgcn_mfma_f32_16x16x32_bf16(
                    af[m], bfv[n], acc[m][n], 0, 0, 0);
    }
}

template<int MASK, bool WRN, bool WRT>
__device__ __forceinline__ void acc_store(const f32x4 acc[4][4],
                                          short* __restrict__ dst,
                                          short* __restrict__ dstT,
                                          const int lane)
{
    const int r0 = (lane >> 4) * 4;
    const int c0 = lane & 15;
#pragma unroll
    for (int m = 0; m < 4; ++m)
#pragma unroll
        for (int n = 0; n < 4; ++n)
#pragma unroll
            for (int j = 0; j < 4; ++j) {
                const int row = m*16 + r0 + j;
                const int col = n*16 + c0;
                float vv = acc[m][n][j];
                if (MASK == 1 && col >= row) vv = 0.f;
                if (MASK == 2 && col >  row) vv = 0.f;
                const short bv = to_bf16(vv);
                if (WRN) dst [row*LSTR + col] = bv;
                if (WRT) dstT[col*LSTR + row] = bv;
            }
}

// init acc (layout row=m*16+(lane>>4)*4+j, col=n*16+(lane&15)) from bf16 LDS mat
__device__ __forceinline__ void acc_init_lds(f32x4 acc[4][4],
                                             const short* __restrict__ src,
                                             const int lane)
{
    const int r0 = (lane >> 4) * 4;
    const int c0 = lane & 15;
#pragma unroll
    for (int m = 0; m < 4; ++m)
#pragma unroll
        for (int n = 0; n < 4; ++n)
#pragma unroll
            for (int j = 0; j < 4; ++j)
                acc[m][n][j] = bf2f(src[(m*16 + r0 + j)*LSTR + n*16 + c0]);
}

// init acc from bf16 GLOBAL 64x64 mat
__device__ __forceinline__ void acc_init_glb(f32x4 acc[4][4],
                                             const short* __restrict__ src,
                                             const int lane)
{
    const int r0 = (lane >> 4) * 4;
    const int c0 = lane & 15;
#pragma unroll
    for (int m = 0; m < 4; ++m)
#pragma unroll
        for (int n = 0; n < 4; ++n)
#pragma unroll
            for (int j = 0; j < 4; ++j)
                acc[m][n][j] = bf2f(src[(m*16 + r0 + j)*64 + n*16 + c0]);
}

// ---------------------------------------------------------------------------
// Scan pass 1, MFMA form. One wave per (chunk, bh).
//   N = stril(Ah Bh^T), C = stril(Ah Kh^T)
//   Y = (I-N)^{-1} Ah,  U = (I-N)^{-1} C Vm     (joint Neumann doubling)
//   G = (I + Y^T Bh) diag(cT);  H = (U^T Bh + Vm^T Kh) diag(cT)
// Stores G,H (f32) for pass2 and Y,U (bf16) for pass3-lite.
// ---------------------------------------------------------------------------
__global__ __launch_bounds__(64)
void scan_pass1_mfma(const float* __restrict__ d, const float* __restrict__ k,
                     const float* __restrict__ v, const float* __restrict__ kk,
                     const float* __restrict__ bb,
                     float* __restrict__ Gbuf, float* __restrict__ Hbuf,
                     short* __restrict__ Yg, short* __restrict__ Ug)
{
    __shared__ short Ah[64*LSTR], XjT[64*LSTR], Bh[64*LSTR], BhT[64*LSTR];
    __shared__ short Kh[64*LSTR], KhT[64*LSTR], Vt[64*LSTR];
    __shared__ short Nb[64*LSTR], Nt[64*LSTR], Cb[64*LSTR], XiT[64*LSTR];
    __shared__ float cTl[64];

    const int chunk = blockIdx.x;
    const int bh = blockIdx.y;
    const int b = bh >> 4, h = bh & 15;
    const int lane = threadIdx.x;

    // ---- staging: hatted matrices, normal + transposed layouts ----
    size_t off = ((size_t)b*TSEQ + (size_t)chunk*CHUNK)*CDIM + h*HSZ + lane;
    float run = 0.f;
    for (int t = 0; t < CHUNK; ++t, off += CDIM) {
        const float de    = d[off];
        const float cprev = run;
        run += logf(de);
        const float ecp = expf(cprev);
        const float ern = expf(-run);
        const short av = to_bf16(-kk[off] * ecp);
        Ah[t*LSTR + lane] = av;  XjT[lane*LSTR + t] = av;
        const short bv = to_bf16(bb[off] * ern);
        Bh[t*LSTR + lane] = bv;  BhT[lane*LSTR + t] = bv;
        const short kv = to_bf16(k[off] * ern);
        Kh[t*LSTR + lane] = kv;  KhT[lane*LSTR + t] = kv;
        Vt[lane*LSTR + t] = to_bf16(v[off]);
    }
    cTl[lane] = expf(run);
    __syncthreads();

    f32x4 xj[4][4], xi[4][4], tmp[4][4];

    // N = stril(Ah Bh^T);  C = stril(Ah Kh^T)
    zero44(tmp);  mm_nt_lds(Ah, Bh, tmp, lane);
    acc_store<1, true, true>(tmp, Nb, Nt, lane);
    zero44(tmp);  mm_nt_lds(Ah, Kh, tmp, lane);
    acc_store<1, true, false>(tmp, Cb, nullptr, lane);
    // Xj accumulator starts as Ah (XjT already = Ah^T)
    acc_init_lds(xj, Ah, lane);
    __syncthreads();

    // Xi = C Vm  ([t][i])
    zero44(xi);  mm_nt_lds(Cb, Vt, xi, lane);
    acc_store<0, false, true>(xi, nullptr, XiT, lane);
    __syncthreads();

    // Neumann doubling: X <- (I + N^{2^k}) X ; N <- N^2  (exact, N^64 = 0)
#pragma unroll 1
    for (int rd = 0; rd < 6; ++rd) {
        mm_nt_lds(Nb, XjT, xj, lane);
        mm_nt_lds(Nb, XiT, xi, lane);
        if (rd < 5) { zero44(tmp); mm_nt_lds(Nb, Nt, tmp, lane); }
        __syncthreads();
        acc_store<0, false, true>(xj, nullptr, XjT, lane);
        acc_store<0, false, true>(xi, nullptr, XiT, lane);
        if (rd < 5) acc_store<0, true, true>(tmp, Nb, Nt, lane);
        __syncthreads();
    }
    // xj = Y [t][j], xi = U [t][i]

    const size_t mb = ((size_t)bh*NCHUNK + chunk)*HSZ*HSZ;
    const int r0 = (lane >> 4) * 4;
    const int c0 = lane & 15;

    // store Y, U (bf16 global) for pass3-lite
#pragma unroll
    for (int m = 0; m < 4; ++m)
#pragma unroll
        for (int n = 0; n < 4; ++n)
#pragma unroll
            for (int j = 0; j < 4; ++j) {
                const int row = m*16 + r0 + j;
                const int col = n*16 + c0;
                Yg[mb + row*64 + col] = to_bf16(xj[m][n][j]);
                Ug[mb + row*64 + col] = to_bf16(xi[m][n][j]);
            }

    float ctv[4];
#pragma unroll
    for (int n = 0; n < 4; ++n) ctv[n] = cTl[n*16 + c0];

    // G = (I + Y^T Bh) diag(cT)
    zero44(tmp);  mm_nt_lds(XjT, BhT, tmp, lane);
#pragma unroll
    for (int m = 0; m < 4; ++m)
#pragma unroll
        for (int n = 0; n < 4; ++n)
#pragma unroll
            for (int j = 0; j < 4; ++j) {
                const int row = m*16 + r0 + j;
                const int col = n*16 + c0;
                const float id = (row == col) ? 1.f : 0.f;
                Gbuf[mb + (size_t)row*HSZ + col] = (tmp[m][n][j] + id) * ctv[n];
            }

    // H = (U^T Bh + Vm^T Kh) diag(cT)
    zero44(tmp);
    mm_nt_lds(XiT, BhT, tmp, lane);
    mm_nt_lds(Vt,  KhT, tmp, lane);
#pragma unroll
    for (int m = 0; m < 4; ++m)
#pragma unroll
        for (int n = 0; n < 4; ++n)
#pragma unroll
            for (int j = 0; j < 4; ++j) {
                const int row = m*16 + r0 + j;
                const int col = n*16 + c0;
                Hbuf[mb + (size_t)row*HSZ + col] = tmp[m][n][j] * ctv[n];
            }
}

// ---------------------------------------------------------------------------
// Scan pass 2 (unchanged, verified): propagate chunk-boundary states.
// ---------------------------------------------------------------------------
__global__ __launch_bounds__(256)
void scan_pass2(const float* __restrict__ Gbuf, const float* __restrict__ Hbuf,
                float* __restrict__ S0buf)
{
    const int rg = blockIdx.x;
    const int bh = blockIdx.y;
    const int tid = threadIdx.x;
    const int il = tid & 15;
    const int q4 = tid >> 4;
    const int row = rg*16 + il;

    __shared__ float Gs[64][68];
    __shared__ float Ssh[16][68];

    float frag[4] = {0.f, 0.f, 0.f, 0.f};
    *(float4*)&Ssh[il][q4*4] = make_float4(0.f, 0.f, 0.f, 0.f);

    for (int c = 0; c < NCHUNK; ++c) {
        const size_t mbase = ((size_t)bh*NCHUNK + c)*HSZ*HSZ;
#pragma unroll
        for (int p = 0; p < 4; ++p) {
            const int f = tid*16 + p*4;
            const int rr = f >> 6, cc = f & 63;
            *(float4*)&Gs[rr][cc] = *(const float4*)(Gbuf + mbase + f);
        }
        *(float4*)(S0buf + mbase + (size_t)row*HSZ + q4*4) =
            make_float4(frag[0], frag[1], frag[2], frag[3]);
        __syncthreads();

        float4 hv = *(const float4*)(Hbuf + mbase + (size_t)row*HSZ + q4*4);
        float a0 = hv.x, a1 = hv.y, a2 = hv.z, a3 = hv.w;
#pragma unroll
        for (int j = 0; j < 64; ++j) {
            const float sj = Ssh[il][j];
            const float4 gv = *(const float4*)&Gs[j][q4*4];
            a0 = fmaf(sj, gv.x, a0);
            a1 = fmaf(sj, gv.y, a1);
            a2 = fmaf(sj, gv.z, a2);
            a3 = fmaf(sj, gv.w, a3);
        }
        __syncthreads();
        frag[0] = a0; frag[1] = a1; frag[2] = a2; frag[3] = a3;
        *(float4*)&Ssh[il][q4*4] = make_float4(a0, a1, a2, a3);
    }
}

// ---------------------------------------------------------------------------
// Scan pass 3 lite: W = Y S0^T + U, then
//   Out = Rh S0^T + tril(Rh Bh^T) W + tril(Rh Kh^T) V
// ---------------------------------------------------------------------------
__global__ __launch_bounds__(64)
void scan_pass3_lite(const float* __restrict__ r, const float* __restrict__ d,
                     const float* __restrict__ k, const float* __restrict__ v,
                     const float* __restrict__ bb,
                     const short* __restrict__ Yg, const short* __restrict__ Ug,
                     const float* __restrict__ S0buf, float* __restrict__ y)
{
    __shared__ short Rh[64*LSTR], Bh[64*LSTR], Kh[64*LSTR], Vt[64*LSTR];
    __shared__ short Yn[64*LSTR], Wt[64*LSTR], P1b[64*LSTR], P2b[64*LSTR];

    const int chunk = blockIdx.x;
    const int bh = blockIdx.y;
    const int b = bh >> 4, h = bh & 15;
    const int lane = threadIdx.x;
    const size_t mb = ((size_t)bh*NCHUNK + chunk)*HSZ*HSZ;

    // stage hatted matrices
    size_t off = ((size_t)b*TSEQ + (size_t)chunk*CHUNK)*CDIM + h*HSZ + lane;
    float run = 0.f;
    for (int t = 0; t < CHUNK; ++t, off += CDIM) {
        run += logf(d[off]);
        const float ern = expf(-run);
        Bh[t*LSTR + lane] = to_bf16(bb[off] * ern);
        Kh[t*LSTR + lane] = to_bf16(k[off]  * ern);
        Rh[t*LSTR + lane] = to_bf16(r[off]  * expf(run));
        Vt[lane*LSTR + t] = to_bf16(v[off]);
    }
    // stage Y (lane copies row `lane`)
    {
        const short* yp = Yg + mb + (size_t)lane*64;
#pragma unroll
        for (int q = 0; q < 8; ++q)
            *(bf16x8*)&Yn[lane*LSTR + q*8] = *(const bf16x8*)(yp + q*8);
    }
    __syncthreads();

    const float* S0g = S0buf + mb;
    f32x4 acc[4][4], oacc[4][4];

    // W = U + Y S0^T  -> Wt [i][t]
    acc_init_glb(acc, Ug + mb, lane);
    mm_nt_gf32(Yn, S0g, acc, lane);
    acc_store<0, false, true>(acc, nullptr, Wt, lane);

    // P1 = tril(Rh Bh^T), P2 = tril(Rh Kh^T) (inclusive)
    zero44(acc);  mm_nt_lds(Rh, Bh, acc, lane);
    acc_store<2, true, false>(acc, P1b, nullptr, lane);
    zero44(acc);  mm_nt_lds(Rh, Kh, acc, lane);
    acc_store<2, true, false>(acc, P2b, nullptr, lane);
    __syncthreads();

    // Out = Rh S0^T + P1 W + P2 V
    zero44(oacc);
    mm_nt_gf32(Rh, S0g, oacc, lane);
    mm_nt_lds(P1b, Wt, oacc, lane);
    mm_nt_lds(P2b, Vt, oacc, lane);

    const int r0 = (lane >> 4) * 4;
    const int c0 = lane & 15;
    float* yb = y + ((size_t)b*TSEQ + (size_t)chunk*CHUNK)*CDIM + h*HSZ;
#pragma unroll
    for (int m = 0; m < 4; ++m)
#pragma unroll
        for (int n = 0; n < 4; ++n)
#pragma unroll
            for (int j = 0; j < 4; ++j)
                yb[(size_t)(m*16 + r0 + j)*CDIM + n*16 + c0] = oacc[m][n][j];
}

// ---------------------------------------------------------------------------
// GroupNorm + rank-1 rwkv residual + *g; writes bf16 (y*g) for the Wo GEMM.
// ---------------------------------------------------------------------------
__global__ __launch_bounds__(1024)
void gn_kernel(const float* __restrict__ r, const float* __restrict__ k,
               const float* __restrict__ v, const float* __restrict__ g,
               const float* __restrict__ rk, const float* __restrict__ gamma,
               const float* __restrict__ beta, const float* __restrict__ y,
               short* __restrict__ ybf)
{
    const int m = blockIdx.x;
    const int c = threadIdx.x;
    const size_t o = (size_t)m*CDIM + c;
    const float yv = y[o];
    float s1 = yv, s2 = yv*yv;
#pragma unroll
    for (int mask = 1; mask < 64; mask <<= 1) {
        s1 += __shfl_xor(s1, mask);
        s2 += __shfl_xor(s2, mask);
    }
    const float mu  = s1 * (1.f/HSZ);
    const float var = s2 * (1.f/HSZ) - mu*mu;
    const float gn  = (yv - mu) * rsqrtf(var + 0.00064f) * gamma[c] + beta[c];

    float p = r[o] * k[o] * rk[c];
#pragma unroll
    for (int mask = 1; mask < 64; mask <<= 1) p += __shfl_xor(p, mask);

    ybf[o] = to_bf16((gn + p * v[o]) * g[o]);
}

// ---------------------------------------------------------------------------
extern "C" void kernel_launch(void* const* d_in, const int* in_sizes, int n_in,
                              void* d_out, int out_size, void* d_ws, size_t ws_size,
                              hipStream_t stream)
{
    const float* x      = (const float*)d_in[0];
    const float* vfirst = (const float*)d_in[1];
    const float* x_r = (const float*)d_in[2];
    const float* x_w = (const float*)d_in[3];
    const float* x_k = (const float*)d_in[4];
    const float* x_v = (const float*)d_in[5];
    const float* x_a = (const float*)d_in[6];
    const float* x_g = (const float*)d_in[7];
    const float* w0  = (const float*)d_in[8];
    const float* w1  = (const float*)d_in[9];
    const float* w2  = (const float*)d_in[10];
    const float* a0  = (const float*)d_in[11];
    const float* a1  = (const float*)d_in[12];
    const float* a2  = (const float*)d_in[13];
    const float* v0p = (const float*)d_in[14];
    const float* v1  = (const float*)d_in[15];
    const float* v2  = (const float*)d_in[16];
    const float* g1  = (const float*)d_in[17];
    const float* g2  = (const float*)d_in[18];
    const float* k_k = (const float*)d_in[19];
    const float* k_a = (const float*)d_in[20];
    const float* r_k = (const float*)d_in[21];
    const float* Wr  = (const float*)d_in[22];
    const float* Wk  = (const float*)d_in[23];
    const float* Wv  = (const float*)d_in[24];
    const float* Wo  = (const float*)d_in[25];
    const float* lng = (const float*)d_in[26];
    const float* lnb = (const float*)d_in[27];
    float* outp = (float*)d_out;

    float* ws = (float*)d_ws;
    const size_t BIG = (size_t)MROWS * CDIM;   // 4 Mi floats = 16 MB
    float* rbuf  = ws + 0*BIG;
    float* kbuf  = ws + 1*BIG;
    float* vbuf  = ws + 2*BIG;
    float* dbuf  = ws + 3*BIG;   // dec; after pass3: ybf/ghbf live here
    float* kkbuf = ws + 4*BIG;
    float* bbuf  = ws + 5*BIG;
    float* gbuf  = ws + 6*BIG;   // vvbuf before post; Hbuf during scan; g after
    float* ybuf  = ws + 7*BIG;   // twbuf before post; Gbuf during scan; y after
    float* hwbuf = ws + 8*BIG;
    float* vwbuf = hwbuf + (size_t)MROWS*64;
    float* awbuf = vwbuf + (size_t)MROWS*32;
    short* wT    = (short*)(awbuf + (size_t)MROWS*64);
    short* WrT = wT;
    short* WkT = WrT + (size_t)CDIM*CDIM;
    short* WvT = WkT + (size_t)CDIM*CDIM;
    short* WoT = WvT + (size_t)CDIM*CDIM;
    short* g1T = WoT + (size_t)CDIM*CDIM;
    short* g2T = g1T + (size_t)128*CDIM;
    short* w1T = g2T + (size_t)CDIM*128;
    short* v1T = w1T + (size_t)64*CDIM;
    short* a1T = v1T + (size_t)32*CDIM;
    short* w2T = a1T + (size_t)64*CDIM;       // [1024][64]
    short* v2T = w2T + (size_t)CDIM*64;       // [1024][32]
    short* a2T = v2T + (size_t)CDIM*32;       // [1024][64]
    short* Yg  = a2T + (size_t)CDIM*64;       // [1024 chunks][64][64] bf16
    short* Ug  = Yg  + (size_t)NBH*NCHUNK*HSZ*HSZ;

    // bf16 first-stage outputs (reuse the hw/vw/aw small region)
    short* hwbf = (short*)hwbuf;
    short* vwbf = hwbf + (size_t)MROWS*64;
    short* awbf = vwbf + (size_t)MROWS*32;

    // second-stage f32 outputs aliased onto dead BIG regions
    float* twbuf = ybuf;
    float* vvbuf = gbuf;
    float* aabuf = outp;

    float* Gbuf  = ybuf;
    float* Hbuf  = gbuf;
    float* S0buf = outp;
    short* ybf   = (short*)dbuf;
    short* ghbf  = (short*)dbuf + 4*1024*1024;

    const dim3 blk(256);

    transpose_cvt<<<dim3(CDIM/32, CDIM/32), blk, 0, stream>>>(Wr, WrT, CDIM, CDIM);
    transpose_cvt<<<dim3(CDIM/32, CDIM/32), blk, 0, stream>>>(Wk, WkT, CDIM, CDIM);
    transpose_cvt<<<dim3(CDIM/32, CDIM/32), blk, 0, stream>>>(Wv, WvT, CDIM, CDIM);
    transpose_cvt<<<dim3(CDIM/32, CDIM/32), blk, 0, stream>>>(Wo, WoT, CDIM, CDIM);
    transpose_cvt<<<dim3(128/32,  CDIM/32), blk, 0, stream>>>(g1, g1T, CDIM, 128);
    transpose_cvt<<<dim3(CDIM/32, 128/32),  blk, 0, stream>>>(g2, g2T, 128, CDIM);
    transpose_cvt<<<dim3(64/32,   CDIM/32), blk, 0, stream>>>(w1, w1T, CDIM, 64);
    transpose_cvt<<<dim3(32/32,   CDIM/32), blk, 0, stream>>>(v1, v1T, CDIM, 32);
    transpose_cvt<<<dim3(64/32,   CDIM/32), blk, 0, stream>>>(a1, a1T, CDIM, 64);
    transpose_cvt<<<dim3(CDIM/32, 64/32),   blk, 0, stream>>>(w2, w2T, 64, CDIM);
    transpose_cvt<<<dim3(CDIM/32, 32/32),   blk, 0, stream>>>(v2, v2T, 32, CDIM);
    transpose_cvt<<<dim3(CDIM/32, 64/32),   blk, 0, stream>>>(a2, a2T, 64, CDIM);

    const dim3 gBig(CDIM/128, MROWS/128);
    const dim3 gOne(1, MROWS/128);

    // big projections (mix fused into A-staging)
    gemm_mfma<128,0,true,false><<<gBig, blk, 0, stream>>>(x, WrT, rbuf, MROWS, CDIM, CDIM, x_r);
    gemm_mfma<128,0,true,false><<<gBig, blk, 0, stream>>>(x, WkT, kbuf, MROWS, CDIM, CDIM, x_k);
    gemm_mfma<128,0,true,false><<<gBig, blk, 0, stream>>>(x, WvT, vbuf, MROWS, CDIM, CDIM, x_v);
    // low-rank first stages (bf16 out)
    gemm_mfma< 64,1,true,true ><<<gOne, blk, 0, stream>>>(x, w1T, hwbf, MROWS,  64, CDIM, x_w);
    gemm_mfma< 32,0,true,true ><<<gOne, blk, 0, stream>>>(x, v1T, vwbf, MROWS,  32, CDIM, x_v);
    gemm_mfma< 64,0,true,true ><<<gOne, blk, 0, stream>>>(x, a1T, awbf, MROWS,  64, CDIM, x_a);
    // low-rank second stages (MFMA, f32 out)
    gemm_mfma<128,0,false,false><<<gBig, blk, 0, stream>>>(hwbf, w2T, twbuf, MROWS, CDIM, 64, nullptr);
    gemm_mfma<128,0,false,false><<<gBig, blk, 0, stream>>>(vwbf, v2T, vvbuf, MROWS, CDIM, 32, nullptr);
    gemm_mfma<128,0,false,false><<<gBig, blk, 0, stream>>>(awbf, a2T, aabuf, MROWS, CDIM, 64, nullptr);

    post_kernel<<<dim3(MROWS), blk, 0, stream>>>(
        twbuf, vvbuf, aabuf, w0, v0p, a0, k_k, k_a, vfirst,
        kbuf, vbuf, dbuf, kkbuf, bbuf);

    // chunked scan (MFMA pass1 + lite pass3, sharing Y/U)
    scan_pass1_mfma<<<dim3(NCHUNK, NBH), dim3(64), 0, stream>>>(
        dbuf, kbuf, vbuf, kkbuf, bbuf, Gbuf, Hbuf, Yg, Ug);
    scan_pass2<<<dim3(4, NBH), dim3(256), 0, stream>>>(Gbuf, Hbuf, S0buf);
    scan_pass3_lite<<<dim3(NCHUNK, NBH), dim3(64), 0, stream>>>(
        rbuf, dbuf, kbuf, vbuf, bbuf, Yg, Ug, S0buf, ybuf);

    gemm_mfma<128,2,true,true ><<<gOne, blk, 0, stream>>>(x, g1T, ghbf, MROWS, 128, CDIM, x_g);
    gemm_mfma<128,0,false,false><<<gBig, blk, 0, stream>>>(ghbf, g2T, gbuf, MROWS, CDIM, 128, nullptr);

    gn_kernel<<<dim3(MROWS), dim3(1024), 0, stream>>>(
        rbuf, kbuf, vbuf, gbuf, r_k, lng, lnb, ybuf, ybf);

    gemm_mfma<128,0,false,false><<<gBig, blk, 0, stream>>>(ybf, WoT, outp, MROWS, CDIM, CDIM, nullptr);
}

// Round 8
// 492.609 us; speedup vs baseline: 1.4611x; 1.4611x over previous
//
#include <hip/hip_runtime.h>
#include <hip/hip_bf16.h>
#include <math.h>

#define TSEQ 2048
#define HEADS 16
#define HSZ 64
#define CDIM 1024
#define MROWS 4096   // B*T
#define CHUNK 64
#define NCHUNK (TSEQ/CHUNK)   // 32
#define NBH 32                // B*HEADS
#define LSTR 68               // LDS row stride (shorts) for 64-wide bf16 mats
#define K2 2048               // doubled K for shared [x|xx] GEMMs

typedef short bf16x8 __attribute__((ext_vector_type(8)));
typedef short bf16x4 __attribute__((ext_vector_type(4)));
typedef float f32x4 __attribute__((ext_vector_type(4)));

__device__ __forceinline__ float sigf(float x) { return 1.0f / (1.0f + expf(-x)); }

__device__ __forceinline__ short to_bf16(float f) {
    __hip_bfloat16 h = __float2bfloat16(f);
    return *reinterpret_cast<short*>(&h);
}

// ---------------------------------------------------------------------------
// A-builder: axbf [4096][2048] bf16 = [ x | shift(x)-x ]
// ---------------------------------------------------------------------------
__global__ __launch_bounds__(256)
void mix_make(const float* __restrict__ x, short* __restrict__ ax)
{
    const int m = blockIdx.x;
    const int cc = threadIdx.x * 4;
    const float4 xv = *(const float4*)(x + (size_t)m*CDIM + cc);
    float4 xp = make_float4(0.f, 0.f, 0.f, 0.f);
    if ((m & (TSEQ-1)) != 0) xp = *(const float4*)(x + (size_t)(m-1)*CDIM + cc);
    bf16x4 a, b;
    a[0] = to_bf16(xv.x); a[1] = to_bf16(xv.y);
    a[2] = to_bf16(xv.z); a[3] = to_bf16(xv.w);
    b[0] = to_bf16(xp.x - xv.x); b[1] = to_bf16(xp.y - xv.y);
    b[2] = to_bf16(xp.z - xv.z); b[3] = to_bf16(xp.w - xv.w);
    *(bf16x4*)(ax + (size_t)m*K2 + cc)        = a;
    *(bf16x4*)(ax + (size_t)m*K2 + CDIM + cc) = b;
}

// ---------------------------------------------------------------------------
// Plain transpose+cvt:  W [K,N] f32 -> Wt [N,K] bf16
// ---------------------------------------------------------------------------
__global__ __launch_bounds__(256)
void transpose_cvt(const float* __restrict__ W, short* __restrict__ Wt,
                   const int K, const int N)
{
    __shared__ float t[32][33];
    const int k0 = blockIdx.y * 32, n0 = blockIdx.x * 32;
    const int lx = threadIdx.x & 31, ly = threadIdx.x >> 5;
#pragma unroll
    for (int i = 0; i < 4; ++i)
        t[ly + i*8][lx] = W[(size_t)(k0 + ly + i*8)*N + n0 + lx];
    __syncthreads();
#pragma unroll
    for (int i = 0; i < 4; ++i)
        Wt[(size_t)(n0 + ly + i*8)*K + k0 + lx] = to_bf16(t[lx][ly + i*8]);
}

// ---------------------------------------------------------------------------
// Scaled-stack transpose: W [1024,N] f32, mix [1024] ->
//   Wt [N][2048] bf16 with Wt[n][k]=W[k][n], Wt[n][1024+k]=mix[k]*W[k][n]
// ---------------------------------------------------------------------------
__global__ __launch_bounds__(256)
void transpose_cvt_scaled(const float* __restrict__ W, const float* __restrict__ mix,
                          short* __restrict__ Wt, const int N)
{
    __shared__ float t[32][33];
    const int k0 = blockIdx.y * 32, n0 = blockIdx.x * 32;
    const int lx = threadIdx.x & 31, ly = threadIdx.x >> 5;
#pragma unroll
    for (int i = 0; i < 4; ++i)
        t[ly + i*8][lx] = W[(size_t)(k0 + ly + i*8)*N + n0 + lx];
    __syncthreads();
    const float mv = mix[k0 + lx];
#pragma unroll
    for (int i = 0; i < 4; ++i) {
        const float w = t[lx][ly + i*8];
        short* base = Wt + (size_t)(n0 + ly + i*8)*K2 + k0 + lx;
        base[0]    = to_bf16(w);
        base[CDIM] = to_bf16(mv * w);
    }
}

// ---------------------------------------------------------------------------
// bf16 MFMA GEMM:  C = A[M,K] @ Bt[N,K]^T.   A always bf16 row-major.
// MODE 0: f32 out to Cptr [M][N].
// MODE 1: split3 — N=3072, writes f32 to three contiguous [M][1024] bufs.
// MODE 2: split4 — N=288, bf16 out: [0,64) tanh ->hw, [64,96)->vw,
//         [96,160)->aw, [160,288) sigmoid ->gh (contiguous sub-buffers).
// ---------------------------------------------------------------------------
template<int BN, int MODE>
__global__ __launch_bounds__(256)
void gemm_mfma(const short* __restrict__ A, const short* __restrict__ Bt,
               void* __restrict__ Cptr, const int M, const int N, const int K)
{
    constexpr int BM = 128, BK = 32;
    constexpr int ASTR = BK + 8;
    constexpr int NWC = (BN >= 128) ? 2 : 1;
    constexpr int NWR = 4 / NWC;
    constexpr int WM = BM / NWR;
    constexpr int WN = BN / NWC;
    constexpr int AM = WM / 16;
    constexpr int AN = WN / 16;

    __shared__ short As[BM * ASTR];
    __shared__ short Bs[BN * ASTR];

    const int tid  = threadIdx.x;
    const int bm   = blockIdx.y * BM;
    const int bn   = blockIdx.x * BN;
    const int wid  = tid >> 6;
    const int lane = tid & 63;
    const int wr   = wid / NWC;
    const int wc   = wid % NWC;
    const int lrow = lane & 15;
    const int koff = (lane >> 4) * 8;

    f32x4 acc[AM][AN];
#pragma unroll
    for (int m = 0; m < AM; ++m)
#pragma unroll
        for (int n = 0; n < AN; ++n)
            acc[m][n] = (f32x4){0.f, 0.f, 0.f, 0.f};

    for (int k0 = 0; k0 < K; k0 += BK) {
        __syncthreads();
#pragma unroll
        for (int p = 0; p < (BM*BK)/(256*8); ++p) {
            const int c = p*256 + tid;
            const int row = c >> 2;
            const int kc  = (c & 3) * 8;
            *(bf16x8*)&As[row*ASTR + kc] =
                *(const bf16x8*)(A + (size_t)(bm+row)*K + k0 + kc);
        }
        {
            constexpr int CHUNKS = (BN*BK)/8;
#pragma unroll
            for (int p = 0; p < (CHUNKS + 255)/256; ++p) {
                const int c = p*256 + tid;
                if ((CHUNKS & 255) == 0 || c < CHUNKS) {
                    const int col = c >> 2;
                    const int kc  = (c & 3) * 8;
                    *(bf16x8*)&Bs[col*ASTR + kc] =
                        *(const bf16x8*)(Bt + (size_t)(bn+col)*K + k0 + kc);
                }
            }
        }
        __syncthreads();

        bf16x8 af[AM], bfv[AN];
#pragma unroll
        for (int m = 0; m < AM; ++m)
            af[m] = *(const bf16x8*)&As[(wr*WM + m*16 + lrow)*ASTR + koff];
#pragma unroll
        for (int n = 0; n < AN; ++n)
            bfv[n] = *(const bf16x8*)&Bs[(wc*WN + n*16 + lrow)*ASTR + koff];
#pragma unroll
        for (int m = 0; m < AM; ++m)
#pragma unroll
            for (int n = 0; n < AN; ++n)
                acc[m][n] = __builtin_amdgcn_mfma_f32_16x16x32_bf16(
                    af[m], bfv[n], acc[m][n], 0, 0, 0);
    }

    const int r0 = (lane >> 4) * 4;
#pragma unroll
    for (int m = 0; m < AM; ++m) {
#pragma unroll
        for (int n = 0; n < AN; ++n) {
#pragma unroll
            for (int j = 0; j < 4; ++j) {
                const int row = bm + wr*WM + m*16 + r0 + j;
                const int col = bn + wc*WN + n*16 + lrow;
                float vv = acc[m][n][j];
                if (MODE == 0) {
                    ((float*)Cptr)[(size_t)row*N + col] = vv;
                } else if (MODE == 1) {
                    ((float*)Cptr)[(size_t)(col >> 10)*((size_t)MROWS*CDIM)
                                   + (size_t)row*CDIM + (col & 1023)] = vv;
                } else {  // MODE 2
                    short* o = (short*)Cptr;
                    if (bn < 64)
                        o[(size_t)row*64 + col] = to_bf16(tanhf(vv));
                    else if (bn < 96)
                        (o + (size_t)MROWS*64)[(size_t)row*32 + col - 64] = to_bf16(vv);
                    else if (bn < 160)
                        (o + (size_t)MROWS*96)[(size_t)row*64 + col - 96] = to_bf16(vv);
                    else
                        (o + (size_t)MROWS*160)[(size_t)row*128 + col - 160] = to_bf16(sigf(vv));
                }
            }
        }
    }
}

// ---------------------------------------------------------------------------
// Per-row post-processing (round-6, verified)
// ---------------------------------------------------------------------------
__global__ __launch_bounds__(256)
void post_kernel(const float* __restrict__ tw, const float* __restrict__ vv,
                 const float* __restrict__ aa,
                 const float* __restrict__ w0, const float* __restrict__ v0p,
                 const float* __restrict__ a0p,
                 const float* __restrict__ k_k, const float* __restrict__ k_a,
                 const float* __restrict__ vfirst,
                 float* __restrict__ kio, float* __restrict__ vio,
                 float* __restrict__ dout, float* __restrict__ kkout,
                 float* __restrict__ bout)
{
    const int m  = blockIdx.x;
    const int c4 = threadIdx.x;
    const size_t o4 = (size_t)m*256 + c4;
    const int cc = c4*4;

    const float4 twv = ((const float4*)tw)[o4];
    const float4 vvv = ((const float4*)vv)[o4];
    const float4 aav = ((const float4*)aa)[o4];
    const float4 kv  = ((const float4*)kio)[o4];
    const float4 vv0 = ((const float4*)vio)[o4];
    const float4 vfv = ((const float4*)vfirst)[o4];
    const float4 w0v = *(const float4*)(w0 + cc);
    const float4 v0v = *(const float4*)(v0p + cc);
    const float4 a0v = *(const float4*)(a0p + cc);
    const float4 kkc = *(const float4*)(k_k + cc);
    const float4 kac = *(const float4*)(k_a + cc);

    float dec[4], vnew[4], av[4], kkr[4], knew[4];
    const float tws[4] = {twv.x, twv.y, twv.z, twv.w};
    const float vvs[4] = {vvv.x, vvv.y, vvv.z, vvv.w};
    const float aas[4] = {aav.x, aav.y, aav.z, aav.w};
    const float ks[4]  = {kv.x, kv.y, kv.z, kv.w};
    const float vs[4]  = {vv0.x, vv0.y, vv0.z, vv0.w};
    const float vfs[4] = {vfv.x, vfv.y, vfv.z, vfv.w};
    const float w0s[4] = {w0v.x, w0v.y, w0v.z, w0v.w};
    const float v0s[4] = {v0v.x, v0v.y, v0v.z, v0v.w};
    const float a0s[4] = {a0v.x, a0v.y, a0v.z, a0v.w};
    const float kks[4] = {kkc.x, kkc.y, kkc.z, kkc.w};
    const float kas[4] = {kac.x, kac.y, kac.z, kac.w};

    float ss = 0.f;
#pragma unroll
    for (int i = 0; i < 4; ++i) {
        dec[i]  = expf(-0.6065306597126334f * sigf(w0s[i] + tws[i]));
        const float sv = sigf(v0s[i] + vvs[i]);
        vnew[i] = vs[i] + (vfs[i] - vs[i]) * sv;
        av[i]   = sigf(a0s[i] + aas[i]);
        kkr[i]  = ks[i] * kks[i];
        knew[i] = ks[i] * (1.f + (av[i] - 1.f) * kas[i]);
        ss = fmaf(kkr[i], kkr[i], ss);
    }
#pragma unroll
    for (int mask = 1; mask < 16; mask <<= 1) ss += __shfl_xor(ss, mask);
    const float inv = fmaxf(rsqrtf(ss + 1e-12f), 1e-12f);

    float4 decv, vnv, knv, kkv4, bv4;
    decv.x = dec[0]; decv.y = dec[1]; decv.z = dec[2]; decv.w = dec[3];
    vnv.x = vnew[0]; vnv.y = vnew[1]; vnv.z = vnew[2]; vnv.w = vnew[3];
    knv.x = knew[0]; knv.y = knew[1]; knv.z = knew[2]; knv.w = knew[3];
    kkv4.x = kkr[0]*inv; kkv4.y = kkr[1]*inv; kkv4.z = kkr[2]*inv; kkv4.w = kkr[3]*inv;
    bv4.x = kkv4.x*av[0]; bv4.y = kkv4.y*av[1]; bv4.z = kkv4.z*av[2]; bv4.w = kkv4.w*av[3];

    ((float4*)dout)[o4]  = decv;
    ((float4*)vio)[o4]   = vnv;
    ((float4*)kio)[o4]   = knv;
    ((float4*)kkout)[o4] = kkv4;
    ((float4*)bout)[o4]  = bv4;
}

// ---------------------------------------------------------------------------
// Scan pass 1 (scalar, round-6 verified): chunk transition G and offset H.
// ---------------------------------------------------------------------------
__global__ __launch_bounds__(128)
void scan_pass1(const float* __restrict__ d, const float* __restrict__ k,
                const float* __restrict__ v, const float* __restrict__ kk,
                const float* __restrict__ bb,
                float* __restrict__ Gbuf, float* __restrict__ Hbuf)
{
    const int chunk = blockIdx.x;
    const int bh = blockIdx.y;
    const int b = bh >> 4, h = bh & 15;
    const int tid = threadIdx.x;
    const int lane = tid & 63;
    const int isH = tid >> 6;

    __shared__ float sv[4][64];   // 0=kk 1=d 2=bb 3=k

    float row[HSZ];
#pragma unroll
    for (int j = 0; j < HSZ; ++j)
        row[j] = (!isH && j == lane) ? 1.f : 0.f;

    size_t off = ((size_t)b*TSEQ + (size_t)chunk*CHUNK) * CDIM + h*HSZ;
    for (int t = 0; t < CHUNK; ++t, off += CDIM) {
        const float vi = isH ? v[off + lane] : 0.f;
        __syncthreads();
        if (!isH) { sv[0][lane] = kk[off + lane]; sv[2][lane] = bb[off + lane]; }
        else      { sv[1][lane] = d[off + lane];  sv[3][lane] = k[off + lane]; }
        __syncthreads();

        float g0 = 0.f, g1 = 0.f, g2 = 0.f, g3 = 0.f;
#pragma unroll
        for (int j4 = 0; j4 < 16; ++j4) {
            const float4 kv = *(const float4*)&sv[0][j4*4];
            g0 = fmaf(row[j4*4+0], kv.x, g0);
            g1 = fmaf(row[j4*4+1], kv.y, g1);
            g2 = fmaf(row[j4*4+2], kv.z, g2);
            g3 = fmaf(row[j4*4+3], kv.w, g3);
        }
        const float ga = -((g0 + g1) + (g2 + g3));

        if (isH) {
#pragma unroll
            for (int j4 = 0; j4 < 16; ++j4) {
                const float4 dv = *(const float4*)&sv[1][j4*4];
                const float4 bv = *(const float4*)&sv[2][j4*4];
                const float4 kv = *(const float4*)&sv[3][j4*4];
                row[j4*4+0] = fmaf(row[j4*4+0], dv.x, fmaf(ga, bv.x, vi * kv.x));
                row[j4*4+1] = fmaf(row[j4*4+1], dv.y, fmaf(ga, bv.y, vi * kv.y));
                row[j4*4+2] = fmaf(row[j4*4+2], dv.z, fmaf(ga, bv.z, vi * kv.z));
                row[j4*4+3] = fmaf(row[j4*4+3], dv.w, fmaf(ga, bv.w, vi * kv.w));
            }
        } else {
#pragma unroll
            for (int j4 = 0; j4 < 16; ++j4) {
                const float4 dv = *(const float4*)&sv[1][j4*4];
                const float4 bv = *(const float4*)&sv[2][j4*4];
                row[j4*4+0] = fmaf(row[j4*4+0], dv.x, ga * bv.x);
                row[j4*4+1] = fmaf(row[j4*4+1], dv.y, ga * bv.y);
                row[j4*4+2] = fmaf(row[j4*4+2], dv.z, ga * bv.z);
                row[j4*4+3] = fmaf(row[j4*4+3], dv.w, ga * bv.w);
            }
        }
    }

    float* dst = (isH ? Hbuf : Gbuf) + (((size_t)bh*NCHUNK + chunk)*HSZ + lane)*HSZ;
#pragma unroll
    for (int j4 = 0; j4 < 16; ++j4)
        *(float4*)&dst[j4*4] = make_float4(row[j4*4+0], row[j4*4+1], row[j4*4+2], row[j4*4+3]);
}

// ---------------------------------------------------------------------------
// Scan pass 2 (unchanged, verified)
// ---------------------------------------------------------------------------
__global__ __launch_bounds__(256)
void scan_pass2(const float* __restrict__ Gbuf, const float* __restrict__ Hbuf,
                float* __restrict__ S0buf)
{
    const int rg = blockIdx.x;
    const int bh = blockIdx.y;
    const int tid = threadIdx.x;
    const int il = tid & 15;
    const int q4 = tid >> 4;
    const int row = rg*16 + il;

    __shared__ float Gs[64][68];
    __shared__ float Ssh[16][68];

    float frag[4] = {0.f, 0.f, 0.f, 0.f};
    *(float4*)&Ssh[il][q4*4] = make_float4(0.f, 0.f, 0.f, 0.f);

    for (int c = 0; c < NCHUNK; ++c) {
        const size_t mbase = ((size_t)bh*NCHUNK + c)*HSZ*HSZ;
#pragma unroll
        for (int p = 0; p < 4; ++p) {
            const int f = tid*16 + p*4;
            const int rr = f >> 6, cc = f & 63;
            *(float4*)&Gs[rr][cc] = *(const float4*)(Gbuf + mbase + f);
        }
        *(float4*)(S0buf + mbase + (size_t)row*HSZ + q4*4) =
            make_float4(frag[0], frag[1], frag[2], frag[3]);
        __syncthreads();

        float4 hv = *(const float4*)(Hbuf + mbase + (size_t)row*HSZ + q4*4);
        float a0 = hv.x, a1 = hv.y, a2 = hv.z, a3 = hv.w;
#pragma unroll
        for (int j = 0; j < 64; ++j) {
            const float sj = Ssh[il][j];
            const float4 gv = *(const float4*)&Gs[j][q4*4];
            a0 = fmaf(sj, gv.x, a0);
            a1 = fmaf(sj, gv.y, a1);
            a2 = fmaf(sj, gv.z, a2);
            a3 = fmaf(sj, gv.w, a3);
        }
        __syncthreads();
        frag[0] = a0; frag[1] = a1; frag[2] = a2; frag[3] = a3;
        *(float4*)&Ssh[il][q4*4] = make_float4(a0, a1, a2, a3);
    }
}

// ---------------------------------------------------------------------------
// Pass-3 MFMA helpers (round-5, verified)
// ---------------------------------------------------------------------------
__device__ __forceinline__ void zero44(f32x4 a[4][4]) {
#pragma unroll
    for (int m = 0; m < 4; ++m)
#pragma unroll
        for (int n = 0; n < 4; ++n) a[m][n] = (f32x4){0.f, 0.f, 0.f, 0.f};
}

__device__ __forceinline__ void mm_nt_lds(const short* __restrict__ Ab,
                                          const short* __restrict__ Bb,
                                          f32x4 acc[4][4], const int lane)
{
    const int lrow = lane & 15;
    const int ko   = (lane >> 4) * 8;
#pragma unroll
    for (int kh = 0; kh < 2; ++kh) {
        bf16x8 af[4], bfv[4];
#pragma unroll
        for (int m = 0; m < 4; ++m)
            af[m] = *(const bf16x8*)&Ab[(m*16 + lrow)*LSTR + kh*32 + ko];
#pragma unroll
        for (int n = 0; n < 4; ++n)
            bfv[n] = *(const bf16x8*)&Bb[(n*16 + lrow)*LSTR + kh*32 + ko];
#pragma unroll
        for (int m = 0; m < 4; ++m)
#pragma unroll
            for (int n = 0; n < 4; ++n)
                acc[m][n] = __builtin_amdgcn_mfma_f32_16x16x32_bf16(
                    af[m], bfv[n], acc[m][n], 0, 0, 0);
    }
}

__device__ __forceinline__ void mm_nt_gf32(const short* __restrict__ Ab,
                                           const float* __restrict__ Bg,
                                           f32x4 acc[4][4], const int lane)
{
    const int lrow = lane & 15;
    const int ko   = (lane >> 4) * 8;
#pragma unroll
    for (int kh = 0; kh < 2; ++kh) {
        bf16x8 af[4], bfv[4];
#pragma unroll
        for (int m = 0; m < 4; ++m)
            af[m] = *(const bf16x8*)&Ab[(m*16 + lrow)*LSTR + kh*32 + ko];
#pragma unroll
        for (int n = 0; n < 4; ++n) {
            const float* p = Bg + (size_t)(n*16 + lrow)*64 + kh*32 + ko;
            const float4 u0 = *(const float4*)p;
            const float4 u1 = *(const float4*)(p + 4);
            bf16x8 bv;
            bv[0] = to_bf16(u0.x); bv[1] = to_bf16(u0.y);
            bv[2] = to_bf16(u0.z); bv[3] = to_bf16(u0.w);
            bv[4] = to_bf16(u1.x); bv[5] = to_bf16(u1.y);
            bv[6] = to_bf16(u1.z); bv[7] = to_bf16(u1.w);
            bfv[n] = bv;
        }
#pragma unroll
        for (int m = 0; m < 4; ++m)
#pragma unroll
            for (int n = 0; n < 4; ++n)
                acc[m][n] = __builtin_amdgcn_mfma_f32_16x16x32_bf16(
                    af[m], bfv[n], acc[m][n], 0, 0, 0);
    }
}

template<int MASK, bool WRN, bool WRT>
__device__ __forceinline__ void acc_store(const f32x4 acc[4][4],
                                          short* __restrict__ dst,
                                          short* __restrict__ dstT,
                                          const int lane)
{
    const int r0 = (lane >> 4) * 4;
    const int c0 = lane & 15;
#pragma unroll
    for (int m = 0; m < 4; ++m)
#pragma unroll
        for (int n = 0; n < 4; ++n)
#pragma unroll
            for (int j = 0; j < 4; ++j) {
                const int row = m*16 + r0 + j;
                const int col = n*16 + c0;
                float vv = acc[m][n][j];
                if (MASK == 1 && col >= row) vv = 0.f;
                if (MASK == 2 && col >  row) vv = 0.f;
                const short bv = to_bf16(vv);
                if (WRN) dst [row*LSTR + col] = bv;
                if (WRT) dstT[col*LSTR + row] = bv;
            }
}

// ---------------------------------------------------------------------------
// Scan pass 3, MFMA chunk form (round-5, verified).
// ---------------------------------------------------------------------------
__global__ __launch_bounds__(64)
void scan_pass3_mfma(const float* __restrict__ r, const float* __restrict__ d,
                     const float* __restrict__ k, const float* __restrict__ v,
                     const float* __restrict__ kk, const float* __restrict__ bb,
                     const float* __restrict__ S0buf, float* __restrict__ y)
{
    __shared__ short Ah[64*LSTR], Bh[64*LSTR], Kh[64*LSTR], Rh[64*LSTR];
    __shared__ short Vt[64*LSTR], Cb[64*LSTR], Nb[64*LSTR], Nt[64*LSTR], Xt[64*LSTR];

    const int chunk = blockIdx.x;
    const int bh = blockIdx.y;
    const int b = bh >> 4, h = bh & 15;
    const int lane = threadIdx.x;

    size_t off = ((size_t)b*TSEQ + (size_t)chunk*CHUNK)*CDIM + h*HSZ + lane;
    float run = 0.f;
    for (int t = 0; t < CHUNK; ++t, off += CDIM) {
        const float de    = d[off];
        const float cprev = run;
        run += logf(de);
        Ah[t*LSTR + lane] = to_bf16(-kk[off] * expf(cprev));
        Bh[t*LSTR + lane] = to_bf16(bb[off] * expf(-run));
        Kh[t*LSTR + lane] = to_bf16(k[off]  * expf(-run));
        Rh[t*LSTR + lane] = to_bf16(r[off]  * expf(run));
        Vt[lane*LSTR + t] = to_bf16(v[off]);
    }
    __syncthreads();

    const float* S0g = S0buf + ((size_t)bh*NCHUNK + chunk)*HSZ*HSZ;

    f32x4 acc[4][4], xacc[4][4];

    zero44(acc);  mm_nt_lds(Ah, Bh, acc, lane);
    acc_store<1, true, true>(acc, Nb, Nt, lane);
    zero44(acc);  mm_nt_lds(Ah, Kh, acc, lane);
    acc_store<1, true, false>(acc, Cb, nullptr, lane);
    __syncthreads();

    zero44(xacc);
    mm_nt_gf32(Ah, S0g, xacc, lane);
    mm_nt_lds(Cb, Vt, xacc, lane);
    acc_store<0, false, true>(xacc, nullptr, Xt, lane);
    __syncthreads();

#pragma unroll 1
    for (int rd = 0; rd < 6; ++rd) {
        mm_nt_lds(Nb, Xt, xacc, lane);
        if (rd < 5) { zero44(acc); mm_nt_lds(Nb, Nt, acc, lane); }
        __syncthreads();
        acc_store<0, false, true>(xacc, nullptr, Xt, lane);
        if (rd < 5) acc_store<0, true, true>(acc, Nb, Nt, lane);
        __syncthreads();
    }

    zero44(acc);  mm_nt_lds(Rh, Bh, acc, lane);
    acc_store<2, true, false>(acc, Cb, nullptr, lane);
    zero44(acc);  mm_nt_lds(Rh, Kh, acc, lane);
    acc_store<2, true, false>(acc, Nb, nullptr, lane);
    __syncthreads();

    zero44(acc);
    mm_nt_gf32(Rh, S0g, acc, lane);
    mm_nt_lds(Cb, Xt, acc, lane);
    mm_nt_lds(Nb, Vt, acc, lane);

    const int r0 = (lane >> 4) * 4;
    const int c0 = lane & 15;
    float* yb = y + ((size_t)b*TSEQ + (size_t)chunk*CHUNK)*CDIM + h*HSZ;
#pragma unroll
    for (int m = 0; m < 4; ++m)
#pragma unroll
        for (int n = 0; n < 4; ++n)
#pragma unroll
            for (int j = 0; j < 4; ++j)
                yb[(size_t)(m*16 + r0 + j)*CDIM + n*16 + c0] = acc[m][n][j];
}

// ---------------------------------------------------------------------------
// GroupNorm + rank-1 rwkv residual + *g; writes bf16 (y*g) for the Wo GEMM.
// ---------------------------------------------------------------------------
__global__ __launch_bounds__(1024)
void gn_kernel(const float* __restrict__ r, const float* __restrict__ k,
               const float* __restrict__ v, const float* __restrict__ g,
               const float* __restrict__ rk, const float* __restrict__ gamma,
               const float* __restrict__ beta, const float* __restrict__ y,
               short* __restrict__ ybf)
{
    const int m = blockIdx.x;
    const int c = threadIdx.x;
    const size_t o = (size_t)m*CDIM + c;
    const float yv = y[o];
    float s1 = yv, s2 = yv*yv;
#pragma unroll
    for (int mask = 1; mask < 64; mask <<= 1) {
        s1 += __shfl_xor(s1, mask);
        s2 += __shfl_xor(s2, mask);
    }
    const float mu  = s1 * (1.f/HSZ);
    const float var = s2 * (1.f/HSZ) - mu*mu;
    const float gn  = (yv - mu) * rsqrtf(var + 0.00064f) * gamma[c] + beta[c];

    float p = r[o] * k[o] * rk[c];
#pragma unroll
    for (int mask = 1; mask < 64; mask <<= 1) p += __shfl_xor(p, mask);

    ybf[o] = to_bf16((gn + p * v[o]) * g[o]);
}

// ---------------------------------------------------------------------------
extern "C" void kernel_launch(void* const* d_in, const int* in_sizes, int n_in,
                              void* d_out, int out_size, void* d_ws, size_t ws_size,
                              hipStream_t stream)
{
    const float* x      = (const float*)d_in[0];
    const float* vfirst = (const float*)d_in[1];
    const float* x_r = (const float*)d_in[2];
    const float* x_w = (const float*)d_in[3];
    const float* x_k = (const float*)d_in[4];
    const float* x_v = (const float*)d_in[5];
    const float* x_a = (const float*)d_in[6];
    const float* x_g = (const float*)d_in[7];
    const float* w0  = (const float*)d_in[8];
    const float* w1  = (const float*)d_in[9];
    const float* w2  = (const float*)d_in[10];
    const float* a0  = (const float*)d_in[11];
    const float* a1  = (const float*)d_in[12];
    const float* a2  = (const float*)d_in[13];
    const float* v0p = (const float*)d_in[14];
    const float* v1  = (const float*)d_in[15];
    const float* v2  = (const float*)d_in[16];
    const float* g1  = (const float*)d_in[17];
    const float* g2  = (const float*)d_in[18];
    const float* k_k = (const float*)d_in[19];
    const float* k_a = (const float*)d_in[20];
    const float* r_k = (const float*)d_in[21];
    const float* Wr  = (const float*)d_in[22];
    const float* Wk  = (const float*)d_in[23];
    const float* Wv  = (const float*)d_in[24];
    const float* Wo  = (const float*)d_in[25];
    const float* lng = (const float*)d_in[26];
    const float* lnb = (const float*)d_in[27];
    float* outp = (float*)d_out;

    float* ws = (float*)d_ws;
    const size_t BIG = (size_t)MROWS * CDIM;   // 4 Mi floats = 16 MB
    float* rbuf  = ws + 0*BIG;                 // r|k|v contiguous for split3
    float* kbuf  = ws + 1*BIG;
    float* vbuf  = ws + 2*BIG;
    float* dbuf  = ws + 3*BIG;                 // decay; ybf after pass3
    float* kkbuf = ws + 4*BIG;
    float* bbuf  = ws + 5*BIG;
    float* gbuf  = ws + 6*BIG;                 // vvbuf pre-post; Hbuf scan; g after
    float* ybuf  = ws + 7*BIG;                 // twbuf pre-post; Gbuf scan; y after
    float* smbuf = ws + 8*BIG;                 // bf16 hw|vw|aw|gh (split4 out)
    short* hwbf  = (short*)smbuf;              // [4096][64]
    // vw at +MROWS*64, aw at +MROWS*96, gh at +MROWS*160 (inside kernel)
    short* wT    = (short*)(smbuf + (size_t)MROWS*160/2);  // after 1.25MB region (f32 units/2)
    short* Brkv = wT;                                    // [3072][2048]
    short* Bsm  = Brkv + (size_t)3072*K2;                // [288][2048]
    short* WoT  = Bsm  + (size_t)288*K2;                 // [1024][1024]
    short* g2T  = WoT  + (size_t)CDIM*CDIM;              // [1024][128]
    short* w2T  = g2T  + (size_t)CDIM*128;               // [1024][64]
    short* v2T  = w2T  + (size_t)CDIM*64;                // [1024][32]
    short* a2T  = v2T  + (size_t)CDIM*32;                // [1024][64]
    short* axbf = a2T  + (size_t)CDIM*64;                // [4096][2048]

    // second-stage f32 outputs aliased onto dead BIG regions
    float* twbuf = ybuf;
    float* vvbuf = gbuf;
    float* aabuf = outp;

    float* Gbuf  = ybuf;
    float* Hbuf  = gbuf;
    float* S0buf = outp;
    short* ybf   = (short*)dbuf;
    short* ghbf  = hwbf + (size_t)MROWS*160;

    const dim3 blk(256);

    // A builder + weight prep
    mix_make<<<dim3(MROWS), blk, 0, stream>>>(x, axbf);
    transpose_cvt_scaled<<<dim3(CDIM/32, CDIM/32), blk, 0, stream>>>(Wr, x_r, Brkv, CDIM);
    transpose_cvt_scaled<<<dim3(CDIM/32, CDIM/32), blk, 0, stream>>>(Wk, x_k, Brkv + (size_t)1024*K2, CDIM);
    transpose_cvt_scaled<<<dim3(CDIM/32, CDIM/32), blk, 0, stream>>>(Wv, x_v, Brkv + (size_t)2048*K2, CDIM);
    transpose_cvt_scaled<<<dim3(64/32,   CDIM/32), blk, 0, stream>>>(w1, x_w, Bsm, 64);
    transpose_cvt_scaled<<<dim3(32/32,   CDIM/32), blk, 0, stream>>>(v1, x_v, Bsm + (size_t)64*K2, 32);
    transpose_cvt_scaled<<<dim3(64/32,   CDIM/32), blk, 0, stream>>>(a1, x_a, Bsm + (size_t)96*K2, 64);
    transpose_cvt_scaled<<<dim3(128/32,  CDIM/32), blk, 0, stream>>>(g1, x_g, Bsm + (size_t)160*K2, 128);
    transpose_cvt<<<dim3(CDIM/32, CDIM/32), blk, 0, stream>>>(Wo, WoT, CDIM, CDIM);
    transpose_cvt<<<dim3(CDIM/32, 128/32),  blk, 0, stream>>>(g2, g2T, 128, CDIM);
    transpose_cvt<<<dim3(CDIM/32, 64/32),   blk, 0, stream>>>(w2, w2T, 64, CDIM);
    transpose_cvt<<<dim3(CDIM/32, 32/32),   blk, 0, stream>>>(v2, v2T, 32, CDIM);
    transpose_cvt<<<dim3(CDIM/32, 64/32),   blk, 0, stream>>>(a2, a2T, 64, CDIM);

    // mega-GEMM: r|k|v  (N=3072, K=2048, 768 blocks = 3/CU)
    gemm_mfma<128,1><<<dim3(3072/128, MROWS/128), blk, 0, stream>>>(
        axbf, Brkv, rbuf, MROWS, 3072, K2);
    // small GEMM: hw|vw|aw|gh with fused acts, bf16 out (N=288)
    gemm_mfma<32,2><<<dim3(288/32, MROWS/128), blk, 0, stream>>>(
        axbf, Bsm, hwbf, MROWS, 288, K2);
    // low-rank second stages (f32 out)
    gemm_mfma<128,0><<<dim3(CDIM/128, MROWS/128), blk, 0, stream>>>(
        hwbf, w2T, twbuf, MROWS, CDIM, 64);
    gemm_mfma<128,0><<<dim3(CDIM/128, MROWS/128), blk, 0, stream>>>(
        hwbf + (size_t)MROWS*64, v2T, vvbuf, MROWS, CDIM, 32);
    gemm_mfma<128,0><<<dim3(CDIM/128, MROWS/128), blk, 0, stream>>>(
        hwbf + (size_t)MROWS*96, a2T, aabuf, MROWS, CDIM, 64);

    post_kernel<<<dim3(MROWS), blk, 0, stream>>>(
        twbuf, vvbuf, aabuf, w0, v0p, a0, k_k, k_a, vfirst,
        kbuf, vbuf, dbuf, kkbuf, bbuf);

    // chunked scan (round-6 known-good trio)
    scan_pass1<<<dim3(NCHUNK, NBH), dim3(128), 0, stream>>>(
        dbuf, kbuf, vbuf, kkbuf, bbuf, Gbuf, Hbuf);
    scan_pass2<<<dim3(4, NBH), dim3(256), 0, stream>>>(Gbuf, Hbuf, S0buf);
    scan_pass3_mfma<<<dim3(NCHUNK, NBH), dim3(64), 0, stream>>>(
        rbuf, dbuf, kbuf, vbuf, kkbuf, bbuf, S0buf, ybuf);

    // g gate: g = ghbf @ g2  (gbuf free after pass2)
    gemm_mfma<128,0><<<dim3(CDIM/128, MROWS/128), blk, 0, stream>>>(
        ghbf, g2T, gbuf, MROWS, CDIM, 128);

    gn_kernel<<<dim3(MROWS), dim3(1024), 0, stream>>>(
        rbuf, kbuf, vbuf, gbuf, r_k, lng, lnb, ybuf, ybf);

    gemm_mfma<128,0><<<dim3(CDIM/128, MROWS/128), blk, 0, stream>>>(
        ybf, WoT, outp, MROWS, CDIM, CDIM);
}

// Round 9
// 469.048 us; speedup vs baseline: 1.5345x; 1.0502x over previous
//
#include <hip/hip_runtime.h>
#include <hip/hip_bf16.h>
#include <math.h>

#define TSEQ 2048
#define HEADS 16
#define HSZ 64
#define CDIM 1024
#define MROWS 4096   // B*T
#define CHUNK 64
#define NCHUNK (TSEQ/CHUNK)   // 32
#define NBH 32                // B*HEADS
#define LSTR 68               // LDS row stride (shorts) for 64-wide bf16 mats
#define K2 2048               // doubled K for shared [x|xx] GEMMs

typedef short bf16x8 __attribute__((ext_vector_type(8)));
typedef short bf16x4 __attribute__((ext_vector_type(4)));
typedef float f32x4 __attribute__((ext_vector_type(4)));

__device__ __forceinline__ float sigf(float x) { return 1.0f / (1.0f + expf(-x)); }

__device__ __forceinline__ short to_bf16(float f) {
    __hip_bfloat16 h = __float2bfloat16(f);
    return *reinterpret_cast<short*>(&h);
}
__device__ __forceinline__ float bf2f(short s) {
    unsigned int u = ((unsigned int)(unsigned short)s) << 16;
    return __uint_as_float(u);
}

// ---------------------------------------------------------------------------
// A-builder: axbf [4096][2048] bf16 = [ x | shift(x)-x ]
// ---------------------------------------------------------------------------
__global__ __launch_bounds__(256)
void mix_make(const float* __restrict__ x, short* __restrict__ ax)
{
    const int m = blockIdx.x;
    const int cc = threadIdx.x * 4;
    const float4 xv = *(const float4*)(x + (size_t)m*CDIM + cc);
    float4 xp = make_float4(0.f, 0.f, 0.f, 0.f);
    if ((m & (TSEQ-1)) != 0) xp = *(const float4*)(x + (size_t)(m-1)*CDIM + cc);
    bf16x4 a, b;
    a[0] = to_bf16(xv.x); a[1] = to_bf16(xv.y);
    a[2] = to_bf16(xv.z); a[3] = to_bf16(xv.w);
    b[0] = to_bf16(xp.x - xv.x); b[1] = to_bf16(xp.y - xv.y);
    b[2] = to_bf16(xp.z - xv.z); b[3] = to_bf16(xp.w - xv.w);
    *(bf16x4*)(ax + (size_t)m*K2 + cc)        = a;
    *(bf16x4*)(ax + (size_t)m*K2 + CDIM + cc) = b;
}

// ---------------------------------------------------------------------------
// Plain transpose+cvt:  W [K,N] f32 -> Wt [N,K] bf16
// ---------------------------------------------------------------------------
__global__ __launch_bounds__(256)
void transpose_cvt(const float* __restrict__ W, short* __restrict__ Wt,
                   const int K, const int N)
{
    __shared__ float t[32][33];
    const int k0 = blockIdx.y * 32, n0 = blockIdx.x * 32;
    const int lx = threadIdx.x & 31, ly = threadIdx.x >> 5;
#pragma unroll
    for (int i = 0; i < 4; ++i)
        t[ly + i*8][lx] = W[(size_t)(k0 + ly + i*8)*N + n0 + lx];
    __syncthreads();
#pragma unroll
    for (int i = 0; i < 4; ++i)
        Wt[(size_t)(n0 + ly + i*8)*K + k0 + lx] = to_bf16(t[lx][ly + i*8]);
}

// ---------------------------------------------------------------------------
// Scaled-stack transpose: W [1024,N] f32, mix [1024] ->
//   Wt [N][2048] bf16 with Wt[n][k]=W[k][n], Wt[n][1024+k]=mix[k]*W[k][n]
// ---------------------------------------------------------------------------
__global__ __launch_bounds__(256)
void transpose_cvt_scaled(const float* __restrict__ W, const float* __restrict__ mix,
                          short* __restrict__ Wt, const int N)
{
    __shared__ float t[32][33];
    const int k0 = blockIdx.y * 32, n0 = blockIdx.x * 32;
    const int lx = threadIdx.x & 31, ly = threadIdx.x >> 5;
#pragma unroll
    for (int i = 0; i < 4; ++i)
        t[ly + i*8][lx] = W[(size_t)(k0 + ly + i*8)*N + n0 + lx];
    __syncthreads();
    const float mv = mix[k0 + lx];
#pragma unroll
    for (int i = 0; i < 4; ++i) {
        const float w = t[lx][ly + i*8];
        short* base = Wt + (size_t)(n0 + ly + i*8)*K2 + k0 + lx;
        base[0]    = to_bf16(w);
        base[CDIM] = to_bf16(mv * w);
    }
}

// ---------------------------------------------------------------------------
// bf16 MFMA GEMM (round-8, verified)
// ---------------------------------------------------------------------------
template<int BN, int MODE>
__global__ __launch_bounds__(256)
void gemm_mfma(const short* __restrict__ A, const short* __restrict__ Bt,
               void* __restrict__ Cptr, const int M, const int N, const int K)
{
    constexpr int BM = 128, BK = 32;
    constexpr int ASTR = BK + 8;
    constexpr int NWC = (BN >= 128) ? 2 : 1;
    constexpr int NWR = 4 / NWC;
    constexpr int WM = BM / NWR;
    constexpr int WN = BN / NWC;
    constexpr int AM = WM / 16;
    constexpr int AN = WN / 16;

    __shared__ short As[BM * ASTR];
    __shared__ short Bs[BN * ASTR];

    const int tid  = threadIdx.x;
    const int bm   = blockIdx.y * BM;
    const int bn   = blockIdx.x * BN;
    const int wid  = tid >> 6;
    const int lane = tid & 63;
    const int wr   = wid / NWC;
    const int wc   = wid % NWC;
    const int lrow = lane & 15;
    const int koff = (lane >> 4) * 8;

    f32x4 acc[AM][AN];
#pragma unroll
    for (int m = 0; m < AM; ++m)
#pragma unroll
        for (int n = 0; n < AN; ++n)
            acc[m][n] = (f32x4){0.f, 0.f, 0.f, 0.f};

    for (int k0 = 0; k0 < K; k0 += BK) {
        __syncthreads();
#pragma unroll
        for (int p = 0; p < (BM*BK)/(256*8); ++p) {
            const int c = p*256 + tid;
            const int row = c >> 2;
            const int kc  = (c & 3) * 8;
            *(bf16x8*)&As[row*ASTR + kc] =
                *(const bf16x8*)(A + (size_t)(bm+row)*K + k0 + kc);
        }
        {
            constexpr int CHUNKS = (BN*BK)/8;
#pragma unroll
            for (int p = 0; p < (CHUNKS + 255)/256; ++p) {
                const int c = p*256 + tid;
                if ((CHUNKS & 255) == 0 || c < CHUNKS) {
                    const int col = c >> 2;
                    const int kc  = (c & 3) * 8;
                    *(bf16x8*)&Bs[col*ASTR + kc] =
                        *(const bf16x8*)(Bt + (size_t)(bn+col)*K + k0 + kc);
                }
            }
        }
        __syncthreads();

        bf16x8 af[AM], bfv[AN];
#pragma unroll
        for (int m = 0; m < AM; ++m)
            af[m] = *(const bf16x8*)&As[(wr*WM + m*16 + lrow)*ASTR + koff];
#pragma unroll
        for (int n = 0; n < AN; ++n)
            bfv[n] = *(const bf16x8*)&Bs[(wc*WN + n*16 + lrow)*ASTR + koff];
#pragma unroll
        for (int m = 0; m < AM; ++m)
#pragma unroll
            for (int n = 0; n < AN; ++n)
                acc[m][n] = __builtin_amdgcn_mfma_f32_16x16x32_bf16(
                    af[m], bfv[n], acc[m][n], 0, 0, 0);
    }

    const int r0 = (lane >> 4) * 4;
#pragma unroll
    for (int m = 0; m < AM; ++m) {
#pragma unroll
        for (int n = 0; n < AN; ++n) {
#pragma unroll
            for (int j = 0; j < 4; ++j) {
                const int row = bm + wr*WM + m*16 + r0 + j;
                const int col = bn + wc*WN + n*16 + lrow;
                float vv = acc[m][n][j];
                if (MODE == 0) {
                    ((float*)Cptr)[(size_t)row*N + col] = vv;
                } else if (MODE == 1) {
                    ((float*)Cptr)[(size_t)(col >> 10)*((size_t)MROWS*CDIM)
                                   + (size_t)row*CDIM + (col & 1023)] = vv;
                } else {  // MODE 2
                    short* o = (short*)Cptr;
                    if (bn < 64)
                        o[(size_t)row*64 + col] = to_bf16(tanhf(vv));
                    else if (bn < 96)
                        (o + (size_t)MROWS*64)[(size_t)row*32 + col - 64] = to_bf16(vv);
                    else if (bn < 160)
                        (o + (size_t)MROWS*96)[(size_t)row*64 + col - 96] = to_bf16(vv);
                    else
                        (o + (size_t)MROWS*160)[(size_t)row*128 + col - 160] = to_bf16(sigf(vv));
                }
            }
        }
    }
}

// ---------------------------------------------------------------------------
// Per-row post-processing (round-6, verified)
// ---------------------------------------------------------------------------
__global__ __launch_bounds__(256)
void post_kernel(const float* __restrict__ tw, const float* __restrict__ vv,
                 const float* __restrict__ aa,
                 const float* __restrict__ w0, const float* __restrict__ v0p,
                 const float* __restrict__ a0p,
                 const float* __restrict__ k_k, const float* __restrict__ k_a,
                 const float* __restrict__ vfirst,
                 float* __restrict__ kio, float* __restrict__ vio,
                 float* __restrict__ dout, float* __restrict__ kkout,
                 float* __restrict__ bout)
{
    const int m  = blockIdx.x;
    const int c4 = threadIdx.x;
    const size_t o4 = (size_t)m*256 + c4;
    const int cc = c4*4;

    const float4 twv = ((const float4*)tw)[o4];
    const float4 vvv = ((const float4*)vv)[o4];
    const float4 aav = ((const float4*)aa)[o4];
    const float4 kv  = ((const float4*)kio)[o4];
    const float4 vv0 = ((const float4*)vio)[o4];
    const float4 vfv = ((const float4*)vfirst)[o4];
    const float4 w0v = *(const float4*)(w0 + cc);
    const float4 v0v = *(const float4*)(v0p + cc);
    const float4 a0v = *(const float4*)(a0p + cc);
    const float4 kkc = *(const float4*)(k_k + cc);
    const float4 kac = *(const float4*)(k_a + cc);

    float dec[4], vnew[4], av[4], kkr[4], knew[4];
    const float tws[4] = {twv.x, twv.y, twv.z, twv.w};
    const float vvs[4] = {vvv.x, vvv.y, vvv.z, vvv.w};
    const float aas[4] = {aav.x, aav.y, aav.z, aav.w};
    const float ks[4]  = {kv.x, kv.y, kv.z, kv.w};
    const float vs[4]  = {vv0.x, vv0.y, vv0.z, vv0.w};
    const float vfs[4] = {vfv.x, vfv.y, vfv.z, vfv.w};
    const float w0s[4] = {w0v.x, w0v.y, w0v.z, w0v.w};
    const float v0s[4] = {v0v.x, v0v.y, v0v.z, v0v.w};
    const float a0s[4] = {a0v.x, a0v.y, a0v.z, a0v.w};
    const float kks[4] = {kkc.x, kkc.y, kkc.z, kkc.w};
    const float kas[4] = {kac.x, kac.y, kac.z, kac.w};

    float ss = 0.f;
#pragma unroll
    for (int i = 0; i < 4; ++i) {
        dec[i]  = expf(-0.6065306597126334f * sigf(w0s[i] + tws[i]));
        const float sv = sigf(v0s[i] + vvs[i]);
        vnew[i] = vs[i] + (vfs[i] - vs[i]) * sv;
        av[i]   = sigf(a0s[i] + aas[i]);
        kkr[i]  = ks[i] * kks[i];
        knew[i] = ks[i] * (1.f + (av[i] - 1.f) * kas[i]);
        ss = fmaf(kkr[i], kkr[i], ss);
    }
#pragma unroll
    for (int mask = 1; mask < 16; mask <<= 1) ss += __shfl_xor(ss, mask);
    const float inv = fmaxf(rsqrtf(ss + 1e-12f), 1e-12f);

    float4 decv, vnv, knv, kkv4, bv4;
    decv.x = dec[0]; decv.y = dec[1]; decv.z = dec[2]; decv.w = dec[3];
    vnv.x = vnew[0]; vnv.y = vnew[1]; vnv.z = vnew[2]; vnv.w = vnew[3];
    knv.x = knew[0]; knv.y = knew[1]; knv.z = knew[2]; knv.w = knew[3];
    kkv4.x = kkr[0]*inv; kkv4.y = kkr[1]*inv; kkv4.z = kkr[2]*inv; kkv4.w = kkr[3]*inv;
    bv4.x = kkv4.x*av[0]; bv4.y = kkv4.y*av[1]; bv4.z = kkv4.z*av[2]; bv4.w = kkv4.w*av[3];

    ((float4*)dout)[o4]  = decv;
    ((float4*)vio)[o4]   = vnv;
    ((float4*)kio)[o4]   = knv;
    ((float4*)kkout)[o4] = kkv4;
    ((float4*)bout)[o4]  = bv4;
}

// ---------------------------------------------------------------------------
// Wave-slice MFMA helpers: each wave computes a 16x64 slice (rows
// [woff,woff+16)) of a 64x64 NT product, acc[4] = 4 column tiles.
// ---------------------------------------------------------------------------
__device__ __forceinline__ void zero4(f32x4 a[4]) {
#pragma unroll
    for (int n = 0; n < 4; ++n) a[n] = (f32x4){0.f, 0.f, 0.f, 0.f};
}

__device__ __forceinline__ void mm_nt_w(const short* __restrict__ Ab,
                                        const short* __restrict__ Bb,
                                        f32x4 acc[4], const int lane, const int woff)
{
    const int lrow = lane & 15;
    const int ko   = (lane >> 4) * 8;
#pragma unroll
    for (int kh = 0; kh < 2; ++kh) {
        const bf16x8 af = *(const bf16x8*)&Ab[(woff + lrow)*LSTR + kh*32 + ko];
        bf16x8 bv[4];
#pragma unroll
        for (int n = 0; n < 4; ++n)
            bv[n] = *(const bf16x8*)&Bb[(n*16 + lrow)*LSTR + kh*32 + ko];
#pragma unroll
        for (int n = 0; n < 4; ++n)
            acc[n] = __builtin_amdgcn_mfma_f32_16x16x32_bf16(af, bv[n], acc[n], 0, 0, 0);
    }
}

// B operand from GLOBAL f32 [64][64] row-major, converted on the fly
__device__ __forceinline__ void mm_nt_gf32_w(const short* __restrict__ Ab,
                                             const float* __restrict__ Bg,
                                             f32x4 acc[4], const int lane, const int woff)
{
    const int lrow = lane & 15;
    const int ko   = (lane >> 4) * 8;
#pragma unroll
    for (int kh = 0; kh < 2; ++kh) {
        const bf16x8 af = *(const bf16x8*)&Ab[(woff + lrow)*LSTR + kh*32 + ko];
#pragma unroll
        for (int n = 0; n < 4; ++n) {
            const float* p = Bg + (size_t)(n*16 + lrow)*64 + kh*32 + ko;
            const float4 u0 = *(const float4*)p;
            const float4 u1 = *(const float4*)(p + 4);
            bf16x8 bv;
            bv[0] = to_bf16(u0.x); bv[1] = to_bf16(u0.y);
            bv[2] = to_bf16(u0.z); bv[3] = to_bf16(u0.w);
            bv[4] = to_bf16(u1.x); bv[5] = to_bf16(u1.y);
            bv[6] = to_bf16(u1.z); bv[7] = to_bf16(u1.w);
            acc[n] = __builtin_amdgcn_mfma_f32_16x16x32_bf16(af, bv, acc[n], 0, 0, 0);
        }
    }
}

// store wave slice. MASK: 0 none, 1 strict lower (col<row), 2 incl lower.
template<int MASK, bool WRN, bool WRT>
__device__ __forceinline__ void acc_store_w(const f32x4 acc[4],
                                            short* __restrict__ dst,
                                            short* __restrict__ dstT,
                                            const int lane, const int woff)
{
    const int r0 = (lane >> 4) * 4;
    const int c0 = lane & 15;
#pragma unroll
    for (int n = 0; n < 4; ++n)
#pragma unroll
        for (int j = 0; j < 4; ++j) {
            const int row = woff + r0 + j;
            const int col = n*16 + c0;
            float vv = acc[n][j];
            if (MASK == 1 && col >= row) vv = 0.f;
            if (MASK == 2 && col >  row) vv = 0.f;
            const short bv = to_bf16(vv);
            if (WRN) dst [row*LSTR + col] = bv;
            if (WRT) dstT[col*LSTR + row] = bv;
        }
}

__device__ __forceinline__ void acc_init_lds_w(f32x4 acc[4],
                                               const short* __restrict__ src,
                                               const int lane, const int woff)
{
    const int r0 = (lane >> 4) * 4;
    const int c0 = lane & 15;
#pragma unroll
    for (int n = 0; n < 4; ++n)
#pragma unroll
        for (int j = 0; j < 4; ++j)
            acc[n][j] = bf2f(src[(woff + r0 + j)*LSTR + n*16 + c0]);
}

__device__ __forceinline__ void acc_init_glb_w(f32x4 acc[4],
                                               const short* __restrict__ src,
                                               const int lane, const int woff)
{
    const int r0 = (lane >> 4) * 4;
    const int c0 = lane & 15;
#pragma unroll
    for (int n = 0; n < 4; ++n)
#pragma unroll
        for (int j = 0; j < 4; ++j)
            acc[n][j] = bf2f(src[(woff + r0 + j)*64 + n*16 + c0]);
}

// ---------------------------------------------------------------------------
// Scan pass 1, WY form, 4 waves/block (algebra verified round 7):
//   N = stril(Ah Bh^T), C = stril(Ah Kh^T)
//   Y = (I-N)^{-1} Ah,  U = (I-N)^{-1} C Vm   (joint Neumann doubling)
//   G = (I + Y^T Bh) diag(cT);  H = (U^T Bh + Vm^T Kh) diag(cT)
// 8 aliased LDS mats (70KB -> 2 blocks/CU). Wave w owns rows [16w,16w+16).
// ---------------------------------------------------------------------------
__global__ __launch_bounds__(256)
void scan_pass1_wy(const float* __restrict__ d, const float* __restrict__ k,
                   const float* __restrict__ v, const float* __restrict__ kk,
                   const float* __restrict__ bb,
                   float* __restrict__ Gbuf, float* __restrict__ Hbuf,
                   short* __restrict__ Yg, short* __restrict__ Ug)
{
    __shared__ short L[8*64*LSTR];
    __shared__ float wsum[4][64];
    __shared__ float cTl[64];
    short* A_  = L + 0*64*LSTR;  // Ah; later XiT
    short* B_  = L + 1*64*LSTR;  // Bh; later XjT
    short* K_  = L + 2*64*LSTR;  // Kh; later Cb
    short* V_  = L + 3*64*LSTR;  // Vt
    short* BT_ = L + 4*64*LSTR;  // BhT
    short* KT_ = L + 5*64*LSTR;  // KhT
    short* N_  = L + 6*64*LSTR;  // Nb
    short* NT_ = L + 7*64*LSTR;  // Nt

    const int chunk = blockIdx.x;
    const int bh = blockIdx.y;
    const int b = bh >> 4, h = bh & 15;
    const int tid = threadIdx.x;
    const int w = tid >> 6;
    const int lane = tid & 63;
    const int woff = w * 16;

    // ---- staging with cross-wave prefix of cumulative log-decay ----
    const size_t base = ((size_t)b*TSEQ + (size_t)chunk*CHUNK + woff)*CDIM + h*HSZ + lane;
    float lc[16];
    float s = 0.f;
#pragma unroll
    for (int t = 0; t < 16; ++t) { s += logf(d[base + (size_t)t*CDIM]); lc[t] = s; }
    wsum[w][lane] = s;
    __syncthreads();
    float pre = 0.f;
#pragma unroll
    for (int w2 = 0; w2 < 3; ++w2) if (w2 < w) pre += wsum[w2][lane];
    if (w == 3) cTl[lane] = expf(pre + s);

#pragma unroll
    for (int t = 0; t < 16; ++t) {
        const int tg = woff + t;
        const size_t off = base + (size_t)t*CDIM;
        const float run   = pre + lc[t];
        const float cprev = (t == 0) ? pre : (pre + lc[t-1]);
        const float ern   = expf(-run);
        A_[tg*LSTR + lane] = to_bf16(-kk[off] * expf(cprev));
        const short bv = to_bf16(bb[off] * ern);
        B_[tg*LSTR + lane] = bv;  BT_[lane*LSTR + tg] = bv;
        const short kv = to_bf16(k[off] * ern);
        K_[tg*LSTR + lane] = kv;  KT_[lane*LSTR + tg] = kv;
        V_[lane*LSTR + tg] = to_bf16(v[off]);
    }
    __syncthreads();

    f32x4 xj[4], xi[4], tmp[4];

    // P1: N = stril(A B^T); xj init from A rows
    zero4(tmp);  mm_nt_w(A_, B_, tmp, lane, woff);
    acc_init_lds_w(xj, A_, lane, woff);
    acc_store_w<1, true, true>(tmp, N_, NT_, lane, woff);
    __syncthreads();                       // B reads done; N/NT visible

    // P2: XjT into B-space; tmpC = stril(A K^T)
    acc_store_w<0, false, true>(xj, nullptr, B_, lane, woff);
    zero4(tmp);  mm_nt_w(A_, K_, tmp, lane, woff);
    __syncthreads();                       // K reads done; XjT written
    acc_store_w<1, true, false>(tmp, K_, nullptr, lane, woff);  // C -> K-space
    __syncthreads();

    // P3: xi = C V ; XiT into A-space (A dead after P2)
    zero4(xi);  mm_nt_w(K_, V_, xi, lane, woff);
    acc_store_w<0, false, true>(xi, nullptr, A_, lane, woff);
    __syncthreads();

    // Neumann doubling (exact: N^64 = 0)
#pragma unroll 1
    for (int rd = 0; rd < 6; ++rd) {
        mm_nt_w(N_, B_, xj, lane, woff);   // xj += N * Y
        mm_nt_w(N_, A_, xi, lane, woff);   // xi += N * U
        if (rd < 5) { zero4(tmp); mm_nt_w(N_, NT_, tmp, lane, woff); }
        __syncthreads();
        acc_store_w<0, false, true>(xj, nullptr, B_, lane, woff);
        acc_store_w<0, false, true>(xi, nullptr, A_, lane, woff);
        if (rd < 5) acc_store_w<0, true, true>(tmp, N_, NT_, lane, woff);
        __syncthreads();
    }
    // xj = Y rows, xi = U rows; B_=XjT, A_=XiT

    const size_t mb = ((size_t)bh*NCHUNK + chunk)*HSZ*HSZ;
    const int r0 = (lane >> 4) * 4;
    const int c0 = lane & 15;

    // Y, U to global (bf16) for pass3-lite
#pragma unroll
    for (int n = 0; n < 4; ++n)
#pragma unroll
        for (int j = 0; j < 4; ++j) {
            const int row = woff + r0 + j;
            const int col = n*16 + c0;
            Yg[mb + row*64 + col] = to_bf16(xj[n][j]);
            Ug[mb + row*64 + col] = to_bf16(xi[n][j]);
        }

    float ctv[4];
#pragma unroll
    for (int n = 0; n < 4; ++n) ctv[n] = cTl[n*16 + c0];

    // G = (I + Y^T Bh) diag(cT)
    zero4(tmp);  mm_nt_w(B_, BT_, tmp, lane, woff);
#pragma unroll
    for (int n = 0; n < 4; ++n)
#pragma unroll
        for (int j = 0; j < 4; ++j) {
            const int row = woff + r0 + j;
            const int col = n*16 + c0;
            const float id = (row == col) ? 1.f : 0.f;
            Gbuf[mb + (size_t)row*HSZ + col] = (tmp[n][j] + id) * ctv[n];
        }

    // H = (U^T Bh + Vm^T Kh) diag(cT)
    zero4(tmp);
    mm_nt_w(A_, BT_, tmp, lane, woff);
    mm_nt_w(V_, KT_, tmp, lane, woff);
#pragma unroll
    for (int n = 0; n < 4; ++n)
#pragma unroll
        for (int j = 0; j < 4; ++j) {
            const int row = woff + r0 + j;
            const int col = n*16 + c0;
            Hbuf[mb + (size_t)row*HSZ + col] = tmp[n][j] * ctv[n];
        }
}

// ---------------------------------------------------------------------------
// Scan pass 2 (unchanged, verified): propagate chunk-boundary states.
// ---------------------------------------------------------------------------
__global__ __launch_bounds__(256)
void scan_pass2(const float* __restrict__ Gbuf, const float* __restrict__ Hbuf,
                float* __restrict__ S0buf)
{
    const int rg = blockIdx.x;
    const int bh = blockIdx.y;
    const int tid = threadIdx.x;
    const int il = tid & 15;
    const int q4 = tid >> 4;
    const int row = rg*16 + il;

    __shared__ float Gs[64][68];
    __shared__ float Ssh[16][68];

    float frag[4] = {0.f, 0.f, 0.f, 0.f};
    *(float4*)&Ssh[il][q4*4] = make_float4(0.f, 0.f, 0.f, 0.f);

    for (int c = 0; c < NCHUNK; ++c) {
        const size_t mbase = ((size_t)bh*NCHUNK + c)*HSZ*HSZ;
#pragma unroll
        for (int p = 0; p < 4; ++p) {
            const int f = tid*16 + p*4;
            const int rr = f >> 6, cc = f & 63;
            *(float4*)&Gs[rr][cc] = *(const float4*)(Gbuf + mbase + f);
        }
        *(float4*)(S0buf + mbase + (size_t)row*HSZ + q4*4) =
            make_float4(frag[0], frag[1], frag[2], frag[3]);
        __syncthreads();

        float4 hv = *(const float4*)(Hbuf + mbase + (size_t)row*HSZ + q4*4);
        float a0 = hv.x, a1 = hv.y, a2 = hv.z, a3 = hv.w;
#pragma unroll
        for (int j = 0; j < 64; ++j) {
            const float sj = Ssh[il][j];
            const float4 gv = *(const float4*)&Gs[j][q4*4];
            a0 = fmaf(sj, gv.x, a0);
            a1 = fmaf(sj, gv.y, a1);
            a2 = fmaf(sj, gv.z, a2);
            a3 = fmaf(sj, gv.w, a3);
        }
        __syncthreads();
        frag[0] = a0; frag[1] = a1; frag[2] = a2; frag[3] = a3;
        *(float4*)&Ssh[il][q4*4] = make_float4(a0, a1, a2, a3);
    }
}

// ---------------------------------------------------------------------------
// Scan pass 3 lite, 4 waves/block (algebra verified round 7):
//   W = Y S0^T + U; Out = Rh S0^T + tril(Rh Bh^T) W + tril(Rh Kh^T) V
// ---------------------------------------------------------------------------
__global__ __launch_bounds__(256)
void scan_pass3_lite4(const float* __restrict__ r, const float* __restrict__ d,
                      const float* __restrict__ k, const float* __restrict__ v,
                      const float* __restrict__ bb,
                      const short* __restrict__ Yg, const short* __restrict__ Ug,
                      const float* __restrict__ S0buf, float* __restrict__ y)
{
    __shared__ short L[8*64*LSTR];
    __shared__ float wsum[4][64];
    short* R_  = L + 0*64*LSTR;
    short* B_  = L + 1*64*LSTR;
    short* K_  = L + 2*64*LSTR;
    short* V_  = L + 3*64*LSTR;
    short* Yn  = L + 4*64*LSTR;
    short* Wt  = L + 5*64*LSTR;
    short* P1b = L + 6*64*LSTR;
    short* P2b = L + 7*64*LSTR;

    const int chunk = blockIdx.x;
    const int bh = blockIdx.y;
    const int b = bh >> 4, h = bh & 15;
    const int tid = threadIdx.x;
    const int w = tid >> 6;
    const int lane = tid & 63;
    const int woff = w * 16;
    const size_t mb = ((size_t)bh*NCHUNK + chunk)*HSZ*HSZ;

    const size_t base = ((size_t)b*TSEQ + (size_t)chunk*CHUNK + woff)*CDIM + h*HSZ + lane;
    float lc[16];
    float s = 0.f;
#pragma unroll
    for (int t = 0; t < 16; ++t) { s += logf(d[base + (size_t)t*CDIM]); lc[t] = s; }
    wsum[w][lane] = s;
    __syncthreads();
    float pre = 0.f;
#pragma unroll
    for (int w2 = 0; w2 < 3; ++w2) if (w2 < w) pre += wsum[w2][lane];

#pragma unroll
    for (int t = 0; t < 16; ++t) {
        const int tg = woff + t;
        const size_t off = base + (size_t)t*CDIM;
        const float run = pre + lc[t];
        const float ern = expf(-run);
        R_[tg*LSTR + lane] = to_bf16(r[off] * expf(run));
        B_[tg*LSTR + lane] = to_bf16(bb[off] * ern);
        K_[tg*LSTR + lane] = to_bf16(k[off]  * ern);
        V_[lane*LSTR + tg] = to_bf16(v[off]);
    }
    // stage Y rows [woff,woff+16)
    {
        const int row = woff + (lane & 15);
        const int cb  = (lane >> 4) * 16;
        const short* yp = Yg + mb + (size_t)row*64 + cb;
        *(bf16x8*)&Yn[row*LSTR + cb]     = *(const bf16x8*)yp;
        *(bf16x8*)&Yn[row*LSTR + cb + 8] = *(const bf16x8*)(yp + 8);
    }
    __syncthreads();

    const float* S0g = S0buf + mb;
    f32x4 a4[4], o4[4];

    // W rows = U rows + Y S0^T -> store transposed to Wt
    acc_init_glb_w(a4, Ug + mb, lane, woff);
    mm_nt_gf32_w(Yn, S0g, a4, lane, woff);
    acc_store_w<0, false, true>(a4, nullptr, Wt, lane, woff);

    // P1 = tril(Rh Bh^T), P2 = tril(Rh Kh^T) (inclusive)
    zero4(a4);  mm_nt_w(R_, B_, a4, lane, woff);
    acc_store_w<2, true, false>(a4, P1b, nullptr, lane, woff);
    zero4(a4);  mm_nt_w(R_, K_, a4, lane, woff);
    acc_store_w<2, true, false>(a4, P2b, nullptr, lane, woff);
    __syncthreads();

    // Out = Rh S0^T + P1 W + P2 V
    zero4(o4);
    mm_nt_gf32_w(R_, S0g, o4, lane, woff);
    mm_nt_w(P1b, Wt, o4, lane, woff);
    mm_nt_w(P2b, V_, o4, lane, woff);

    const int r0 = (lane >> 4) * 4;
    const int c0 = lane & 15;
    float* yb = y + ((size_t)b*TSEQ + (size_t)chunk*CHUNK)*CDIM + h*HSZ;
#pragma unroll
    for (int n = 0; n < 4; ++n)
#pragma unroll
        for (int j = 0; j < 4; ++j)
            yb[(size_t)(woff + r0 + j)*CDIM + n*16 + c0] = o4[n][j];
}

// ---------------------------------------------------------------------------
// GroupNorm + rank-1 rwkv residual + *g; writes bf16 (y*g) for the Wo GEMM.
// ---------------------------------------------------------------------------
__global__ __launch_bounds__(1024)
void gn_kernel(const float* __restrict__ r, const float* __restrict__ k,
               const float* __restrict__ v, const float* __restrict__ g,
               const float* __restrict__ rk, const float* __restrict__ gamma,
               const float* __restrict__ beta, const float* __restrict__ y,
               short* __restrict__ ybf)
{
    const int m = blockIdx.x;
    const int c = threadIdx.x;
    const size_t o = (size_t)m*CDIM + c;
    const float yv = y[o];
    float s1 = yv, s2 = yv*yv;
#pragma unroll
    for (int mask = 1; mask < 64; mask <<= 1) {
        s1 += __shfl_xor(s1, mask);
        s2 += __shfl_xor(s2, mask);
    }
    const float mu  = s1 * (1.f/HSZ);
    const float var = s2 * (1.f/HSZ) - mu*mu;
    const float gn  = (yv - mu) * rsqrtf(var + 0.00064f) * gamma[c] + beta[c];

    float p = r[o] * k[o] * rk[c];
#pragma unroll
    for (int mask = 1; mask < 64; mask <<= 1) p += __shfl_xor(p, mask);

    ybf[o] = to_bf16((gn + p * v[o]) * g[o]);
}

// ---------------------------------------------------------------------------
extern "C" void kernel_launch(void* const* d_in, const int* in_sizes, int n_in,
                              void* d_out, int out_size, void* d_ws, size_t ws_size,
                              hipStream_t stream)
{
    const float* x      = (const float*)d_in[0];
    const float* vfirst = (const float*)d_in[1];
    const float* x_r = (const float*)d_in[2];
    const float* x_w = (const float*)d_in[3];
    const float* x_k = (const float*)d_in[4];
    const float* x_v = (const float*)d_in[5];
    const float* x_a = (const float*)d_in[6];
    const float* x_g = (const float*)d_in[7];
    const float* w0  = (const float*)d_in[8];
    const float* w1  = (const float*)d_in[9];
    const float* w2  = (const float*)d_in[10];
    const float* a0  = (const float*)d_in[11];
    const float* a1  = (const float*)d_in[12];
    const float* a2  = (const float*)d_in[13];
    const float* v0p = (const float*)d_in[14];
    const float* v1  = (const float*)d_in[15];
    const float* v2  = (const float*)d_in[16];
    const float* g1  = (const float*)d_in[17];
    const float* g2  = (const float*)d_in[18];
    const float* k_k = (const float*)d_in[19];
    const float* k_a = (const float*)d_in[20];
    const float* r_k = (const float*)d_in[21];
    const float* Wr  = (const float*)d_in[22];
    const float* Wk  = (const float*)d_in[23];
    const float* Wv  = (const float*)d_in[24];
    const float* Wo  = (const float*)d_in[25];
    const float* lng = (const float*)d_in[26];
    const float* lnb = (const float*)d_in[27];
    float* outp = (float*)d_out;

    float* ws = (float*)d_ws;
    const size_t BIG = (size_t)MROWS * CDIM;   // 4 Mi floats = 16 MB
    float* rbuf  = ws + 0*BIG;                 // r|k|v contiguous for split3
    float* kbuf  = ws + 1*BIG;
    float* vbuf  = ws + 2*BIG;
    float* dbuf  = ws + 3*BIG;                 // decay; ybf after pass3
    float* kkbuf = ws + 4*BIG;
    float* bbuf  = ws + 5*BIG;
    float* gbuf  = ws + 6*BIG;                 // vvbuf pre-post; Hbuf scan; g after
    float* ybuf  = ws + 7*BIG;                 // twbuf pre-post; Gbuf scan; y after
    float* smbuf = ws + 8*BIG;                 // bf16 hw|vw|aw|gh (split4 out)
    short* hwbf  = (short*)smbuf;              // [4096][64]
    // vw at +MROWS*64, aw at +MROWS*96, gh at +MROWS*160 (inside kernel).
    // NOTE: wT region starts AT ghbf — Brkv's head is overwritten by the
    // small GEMM's gh output, but Brkv is dead by then (stream order).
    short* wT    = (short*)(smbuf + (size_t)MROWS*160/2);
    short* Brkv = wT;                                    // [3072][2048]
    short* Bsm  = Brkv + (size_t)3072*K2;                // [288][2048]
    short* WoT  = Bsm  + (size_t)288*K2;                 // [1024][1024]
    short* g2T  = WoT  + (size_t)CDIM*CDIM;              // [1024][128]
    short* w2T  = g2T  + (size_t)CDIM*128;               // [1024][64]
    short* v2T  = w2T  + (size_t)CDIM*64;                // [1024][32]
    short* a2T  = v2T  + (size_t)CDIM*32;                // [1024][64]
    short* axbf = a2T  + (size_t)CDIM*64;                // [4096][2048]

    // Y/U (bf16, 2 x 4.19M shorts) alias axbf exactly — axbf dead after the
    // projection GEMMs, pass1_wy writes Y/U afterwards (stream order).
    short* Yg = axbf;
    short* Ug = axbf + (size_t)NBH*NCHUNK*HSZ*HSZ;

    // second-stage f32 outputs aliased onto dead BIG regions
    float* twbuf = ybuf;
    float* vvbuf = gbuf;
    float* aabuf = outp;

    float* Gbuf  = ybuf;
    float* Hbuf  = gbuf;
    float* S0buf = outp;
    short* ybf   = (short*)dbuf;
    short* ghbf  = hwbf + (size_t)MROWS*160;

    const dim3 blk(256);

    // A builder + weight prep
    mix_make<<<dim3(MROWS), blk, 0, stream>>>(x, axbf);
    transpose_cvt_scaled<<<dim3(CDIM/32, CDIM/32), blk, 0, stream>>>(Wr, x_r, Brkv, CDIM);
    transpose_cvt_scaled<<<dim3(CDIM/32, CDIM/32), blk, 0, stream>>>(Wk, x_k, Brkv + (size_t)1024*K2, CDIM);
    transpose_cvt_scaled<<<dim3(CDIM/32, CDIM/32), blk, 0, stream>>>(Wv, x_v, Brkv + (size_t)2048*K2, CDIM);
    transpose_cvt_scaled<<<dim3(64/32,   CDIM/32), blk, 0, stream>>>(w1, x_w, Bsm, 64);
    transpose_cvt_scaled<<<dim3(32/32,   CDIM/32), blk, 0, stream>>>(v1, x_v, Bsm + (size_t)64*K2, 32);
    transpose_cvt_scaled<<<dim3(64/32,   CDIM/32), blk, 0, stream>>>(a1, x_a, Bsm + (size_t)96*K2, 64);
    transpose_cvt_scaled<<<dim3(128/32,  CDIM/32), blk, 0, stream>>>(g1, x_g, Bsm + (size_t)160*K2, 128);
    transpose_cvt<<<dim3(CDIM/32, CDIM/32), blk, 0, stream>>>(Wo, WoT, CDIM, CDIM);
    transpose_cvt<<<dim3(CDIM/32, 128/32),  blk, 0, stream>>>(g2, g2T, 128, CDIM);
    transpose_cvt<<<dim3(CDIM/32, 64/32),   blk, 0, stream>>>(w2, w2T, 64, CDIM);
    transpose_cvt<<<dim3(CDIM/32, 32/32),   blk, 0, stream>>>(v2, v2T, 32, CDIM);
    transpose_cvt<<<dim3(CDIM/32, 64/32),   blk, 0, stream>>>(a2, a2T, 64, CDIM);

    // mega-GEMM: r|k|v  (N=3072, K=2048)
    gemm_mfma<128,1><<<dim3(3072/128, MROWS/128), blk, 0, stream>>>(
        axbf, Brkv, rbuf, MROWS, 3072, K2);
    // small GEMM: hw|vw|aw|gh with fused acts, bf16 out (N=288)
    gemm_mfma<32,2><<<dim3(288/32, MROWS/128), blk, 0, stream>>>(
        axbf, Bsm, hwbf, MROWS, 288, K2);
    // low-rank second stages (f32 out)
    gemm_mfma<128,0><<<dim3(CDIM/128, MROWS/128), blk, 0, stream>>>(
        hwbf, w2T, twbuf, MROWS, CDIM, 64);
    gemm_mfma<128,0><<<dim3(CDIM/128, MROWS/128), blk, 0, stream>>>(
        hwbf + (size_t)MROWS*64, v2T, vvbuf, MROWS, CDIM, 32);
    gemm_mfma<128,0><<<dim3(CDIM/128, MROWS/128), blk, 0, stream>>>(
        hwbf + (size_t)MROWS*96, a2T, aabuf, MROWS, CDIM, 64);

    post_kernel<<<dim3(MROWS), blk, 0, stream>>>(
        twbuf, vvbuf, aabuf, w0, v0p, a0, k_k, k_a, vfirst,
        kbuf, vbuf, dbuf, kkbuf, bbuf);

    // chunked scan: 4-wave WY pass1 + pass2 + 4-wave lite pass3
    scan_pass1_wy<<<dim3(NCHUNK, NBH), blk, 0, stream>>>(
        dbuf, kbuf, vbuf, kkbuf, bbuf, Gbuf, Hbuf, Yg, Ug);
    scan_pass2<<<dim3(4, NBH), blk, 0, stream>>>(Gbuf, Hbuf, S0buf);
    scan_pass3_lite4<<<dim3(NCHUNK, NBH), blk, 0, stream>>>(
        rbuf, dbuf, kbuf, vbuf, bbuf, Yg, Ug, S0buf, ybuf);

    // g gate: g = ghbf @ g2  (gbuf free after pass2)
    gemm_mfma<128,0><<<dim3(CDIM/128, MROWS/128), blk, 0, stream>>>(
        ghbf, g2T, gbuf, MROWS, CDIM, 128);

    gn_kernel<<<dim3(MROWS), dim3(1024), 0, stream>>>(
        rbuf, kbuf, vbuf, gbuf, r_k, lng, lnb, ybuf, ybf);

    gemm_mfma<128,0><<<dim3(CDIM/128, MROWS/128), blk, 0, stream>>>(
        ybf, WoT, outp, MROWS, CDIM, CDIM);
}